// Round 2
// baseline (1318.425 us; speedup 1.0000x reference)
//
#include <hip/hip_runtime.h>

// ---------------------------------------------------------------------------
// HeteroGNN fused pipeline for MI355X (gfx950).
//   loc_h = relu(loc_x @ W_loc + b_loc)          [100000, 64]
//   evt_h = relu(evt_x @ W_evt + b_evt)          [200000, 64]
//   agg   = segment_mean(evt_h[src] -> dst)      [100000, 64]
//   h2    = relu(agg @ W_l + b_l + loc_h @ W_r)  [100000, 64]
//   h1    = relu(h2 @ W_h1 + b_h1)               [100000, 32]
//   out   = h1 @ W_h2 + b_h2                     [100000]
// Dtypes of the float tensors (bf16 vs fp32) and edge_index (int32 vs int64)
// are detected at runtime per tensor (flags in ws), since round-1 NaNs proved
// the static bf16 assumption wrong for at least some tensors.
// ---------------------------------------------------------------------------

#define N_LOC 100000
#define N_EVT 200000
#define E_CNT 1000000

typedef __attribute__((ext_vector_type(8))) short short8;   // 8 x bf16
typedef __attribute__((ext_vector_type(4))) float floatx4;  // MFMA C/D frag

__device__ __forceinline__ float b2f(unsigned short u) {
    unsigned int x = ((unsigned int)u) << 16;
    return __builtin_bit_cast(float, x);
}
__device__ __forceinline__ unsigned short f2b(float f) {
    unsigned int x = __builtin_bit_cast(unsigned int, f);
    unsigned int r = (x + 0x7fffu + ((x >> 16) & 1u)) >> 16;  // RNE
    return (unsigned short)r;
}
__device__ __forceinline__ float rdlane(float v, int k) {
    return __builtin_bit_cast(float,
        __builtin_amdgcn_readlane(__builtin_bit_cast(int, v), k));
}
__device__ __forceinline__ float loadf(const void* p, int f32, size_t i) {
    return f32 ? ((const float*)p)[i] : b2f(((const unsigned short*)p)[i]);
}

// ---------------------------------------------------------------------------
// K_detect: per-tensor dtype detection. One block / 64 threads.
// bf16 randn-scale data: exponent field < 0x90 always. fp32 data read as
// half-words: low halves have uniform exponent bits -> ~22% of all halves
// have exp >= 0x90. All-zero tensors classify bf16; zeros decode to 0.0
// under either reading, so that's harmless.
// flags[i]: 1 = fp32 (i = input slot). flags[2]: 1 = edge_index is int64.
// ---------------------------------------------------------------------------
__global__ void detect_kernel(
    const void* t0, const void* t1, const int* eidx,
    const void* t3, const void* t4, const void* t5, const void* t6,
    const void* t7, const void* t8, const void* t9, const void* t10,
    const void* t11, const void* t12, const void* t13, int* flags) {
    const void* ptrs[13] = {t0, t1, t3, t4, t5, t6, t7, t8, t9, t10, t11, t12, t13};
    const int   cnts[13] = {12800000, 25600000, 8192, 64, 8192, 64,
                            4096, 64, 4096, 2048, 32, 32, 1};
    const int   slot[13] = {0, 1, 3, 4, 5, 6, 7, 8, 9, 10, 11, 12, 13};
    int lane = threadIdx.x;
    for (int t = 0; t < 13; ++t) {
        int nsamp = 2 * cnts[t];
        if (nsamp > 1024) nsamp = 1024;
        const unsigned short* h = (const unsigned short*)ptrs[t];
        int susp = 0;
        for (int i = lane; i < nsamp; i += 64) {
            int e = (h[i] >> 7) & 0xFF;
            if (e >= 0x90) susp++;
        }
        for (int d = 1; d < 64; d <<= 1) susp += __shfl_xor(susp, d);
        if (lane == 0) flags[slot[t]] = (susp * 16 >= nsamp) ? 1 : 0;
    }
    // int64 edge_index: all odd 32-bit words are zero (values < 1e5 >= 0).
    int oddnz = 0, evennz = 0;
    for (int i = lane; i < 128; i += 64) {
        if (eidx[2 * i] != 0) evennz++;
        if (eidx[2 * i + 1] != 0) oddnz++;
    }
    for (int d = 1; d < 64; d <<= 1) {
        oddnz += __shfl_xor(oddnz, d);
        evennz += __shfl_xor(evennz, d);
    }
    if (lane == 0) flags[2] = (oddnz == 0 && evennz > 32) ? 1 : 0;
}

// ---------------------------------------------------------------------------
// K_zero: zero msg + cnt (graph-capture-safe replacement for memset).
// ---------------------------------------------------------------------------
__global__ __launch_bounds__(256) void zero_kernel(float4* p, int n4) {
    int i = blockIdx.x * 256 + threadIdx.x;
    if (i < n4) p[i] = make_float4(0.f, 0.f, 0.f, 0.f);
}

// ---------------------------------------------------------------------------
// K0: permute W [128,64] row-major into MFMA B-fragment order (bf16 out).
// Lane l of frag f=t*4+kk holds B[k=kk*32+(l>>4)*8+j][n=t*16+(l&15)], j=0..7.
// ---------------------------------------------------------------------------
__global__ __launch_bounds__(256) void permute_w_kernel(
    const void* W, unsigned short* Wp, const int* flags, int slot) {
    int f32 = flags[slot];
    int idx  = blockIdx.x * 256 + threadIdx.x;   // 0..1023
    int f    = idx >> 6;
    int lane = idx & 63;
    int t  = f >> 2;
    int kk = f & 3;
    int n  = t * 16 + (lane & 15);
    int k0 = kk * 32 + (lane >> 4) * 8;
    unsigned short tmp[8];
#pragma unroll
    for (int j = 0; j < 8; ++j) {
        size_t src = (size_t)(k0 + j) * 64 + n;
        tmp[j] = f32 ? f2b(((const float*)W)[src])
                     : ((const unsigned short*)W)[src];
    }
#pragma unroll
    for (int j = 0; j < 8; ++j) Wp[(size_t)idx * 8 + j] = tmp[j];
}

// ---------------------------------------------------------------------------
// K1: Y[M,64] = relu(X[M,128] @ W[128,64] + b), MFMA 16x16x32, bf16 out.
// Block = 4 waves; wave = 16-row strip; B frags in 64 VGPRs; no LDS.
// ---------------------------------------------------------------------------
__global__ __launch_bounds__(256) void proj_kernel(
    const void* __restrict__ X,
    const unsigned short* __restrict__ Wp,
    const void* __restrict__ bias,
    unsigned short* __restrict__ Y, int M,
    const int* __restrict__ flags, int sx, int sb) {
    int fx = flags[sx], fb = flags[sb];
    int tid  = threadIdx.x;
    int lane = tid & 63;
    int wv   = tid >> 6;
    int l15  = lane & 15;
    int quad = lane >> 4;
    int row_base = blockIdx.x * 64 + wv * 16;

    short8 b[16];
#pragma unroll
    for (int f = 0; f < 16; ++f)
        b[f] = *reinterpret_cast<const short8*>(Wp + ((size_t)(f * 64 + lane)) * 8);

    int m = row_base + l15;
    short8 a[4];
#pragma unroll
    for (int kk = 0; kk < 4; ++kk) a[kk] = (short8)0;
    if (m < M) {
        if (fx) {
            const float* xr = (const float*)X + (size_t)m * 128 + quad * 8;
#pragma unroll
            for (int kk = 0; kk < 4; ++kk) {
                float4 p0 = *reinterpret_cast<const float4*>(xr + kk * 32);
                float4 p1 = *reinterpret_cast<const float4*>(xr + kk * 32 + 4);
                short8 v;
                v[0] = (short)f2b(p0.x); v[1] = (short)f2b(p0.y);
                v[2] = (short)f2b(p0.z); v[3] = (short)f2b(p0.w);
                v[4] = (short)f2b(p1.x); v[5] = (short)f2b(p1.y);
                v[6] = (short)f2b(p1.z); v[7] = (short)f2b(p1.w);
                a[kk] = v;
            }
        } else {
            const unsigned short* xr = (const unsigned short*)X + (size_t)m * 128 + quad * 8;
#pragma unroll
            for (int kk = 0; kk < 4; ++kk)
                a[kk] = *reinterpret_cast<const short8*>(xr + kk * 32);
        }
    }

    floatx4 acc[4];
#pragma unroll
    for (int t = 0; t < 4; ++t) acc[t] = (floatx4)0.0f;
#pragma unroll
    for (int kk = 0; kk < 4; ++kk) {
#pragma unroll
        for (int t = 0; t < 4; ++t)
            acc[t] = __builtin_amdgcn_mfma_f32_16x16x32_bf16(
                a[kk], b[t * 4 + kk], acc[t], 0, 0, 0);
    }

    // C/D layout: col = lane&15, row = quad*4 + r  [verified m89]
#pragma unroll
    for (int t = 0; t < 4; ++t) {
        float bv = loadf(bias, fb, t * 16 + l15);
#pragma unroll
        for (int r = 0; r < 4; ++r) {
            int row = row_base + quad * 4 + r;
            if (row < M) {
                float v = acc[t][r] + bv;
                v = v > 0.0f ? v : 0.0f;
                Y[(size_t)row * 64 + t * 16 + l15] = f2b(v);
            }
        }
    }
}

// ---------------------------------------------------------------------------
// K2: scatter-mean accumulate. 16 threads/edge, 4 columns each, fp32 atomics.
// ---------------------------------------------------------------------------
__global__ __launch_bounds__(256) void scatter_kernel(
    const unsigned short* __restrict__ evt_h,
    const int* __restrict__ eidx,
    float* __restrict__ msg, float* __restrict__ cnt,
    const int* __restrict__ flags) {
    int gid = blockIdx.x * 256 + threadIdx.x;
    int e = gid >> 4;
    int t = gid & 15;
    if (e >= E_CNT) return;
    int src, dst;
    if (flags[2]) {
        const long long* e64 = (const long long*)eidx;
        src = (int)e64[e];
        dst = (int)e64[E_CNT + e];
    } else {
        src = eidx[e];
        dst = eidx[E_CNT + e];
    }
    if ((unsigned)src >= (unsigned)N_EVT || (unsigned)dst >= (unsigned)N_LOC) return;
    const ushort4 raw = *reinterpret_cast<const ushort4*>(
        evt_h + (size_t)src * 64 + t * 4);
    float* q = msg + (size_t)dst * 64 + t * 4;
    atomicAdd(q + 0, b2f(raw.x));
    atomicAdd(q + 1, b2f(raw.y));
    atomicAdd(q + 2, b2f(raw.z));
    atomicAdd(q + 3, b2f(raw.w));
    if (t == 0) atomicAdd(cnt + dst, 1.0f);
}

// ---------------------------------------------------------------------------
// K3: fused SAGE + MLP head. Weights in LDS (fp32). Wave = 4 rows/iter,
// lane = output column, k-broadcast via v_readlane.
// ---------------------------------------------------------------------------
__global__ __launch_bounds__(256) void head_kernel(
    const float* __restrict__ msg, const float* __restrict__ cnt,
    const unsigned short* __restrict__ loc_h,
    const void* __restrict__ Wl, const void* __restrict__ bl,
    const void* __restrict__ Wr,
    const void* __restrict__ Wh1, const void* __restrict__ bh1,
    const void* __restrict__ Wh2, const void* __restrict__ bh2,
    void* __restrict__ out, int N, const int* __restrict__ flags) {
    __shared__ float sWl[64 * 64];
    __shared__ float sWr[64 * 64];
    __shared__ float sWh1[64 * 32];
    __shared__ float sbl[64];
    __shared__ float sbh1[32];
    __shared__ float sWh2[32];
    __shared__ float sbh2;

    int tid = threadIdx.x;
    int fWl = flags[7], fWr = flags[9], fWh1 = flags[10];
    for (int i = tid; i < 64 * 64; i += 256) {
        sWl[i] = loadf(Wl, fWl, i);
        sWr[i] = loadf(Wr, fWr, i);
    }
    for (int i = tid; i < 64 * 32; i += 256) sWh1[i] = loadf(Wh1, fWh1, i);
    if (tid < 64) sbl[tid] = loadf(bl, flags[8], tid);
    if (tid < 32) {
        sbh1[tid] = loadf(bh1, flags[11], tid);
        sWh2[tid] = loadf(Wh2, flags[12], tid);
    }
    if (tid == 0) sbh2 = loadf(bh2, flags[13], 0);
    int f_out = flags[0];  // output dtype follows loc_x's dtype
    __syncthreads();

    int lane = tid & 63;
    int wv   = tid >> 6;
    int gw     = blockIdx.x * 4 + wv;
    int totalW = gridDim.x * 4;
    int j2 = lane & 31;

    for (int base = gw * 4; base < N; base += totalW * 4) {
        float agg[4], root[4], acc[4];
#pragma unroll
        for (int r = 0; r < 4; ++r) {
            int row = base + r;
            if (row < N) {
                float c   = cnt[row];
                float inv = 1.0f / fmaxf(c, 1.0f);
                agg[r]  = msg[(size_t)row * 64 + lane] * inv;
                root[r] = b2f(loc_h[(size_t)row * 64 + lane]);
            } else {
                agg[r] = 0.0f;
                root[r] = 0.0f;
            }
            acc[r] = sbl[lane];
        }
#pragma unroll 4
        for (int k = 0; k < 64; ++k) {
            float wl = sWl[k * 64 + lane];
            float wr = sWr[k * 64 + lane];
#pragma unroll
            for (int r = 0; r < 4; ++r)
                acc[r] += rdlane(agg[r], k) * wl + rdlane(root[r], k) * wr;
        }
        float h2[4];
#pragma unroll
        for (int r = 0; r < 4; ++r) h2[r] = fmaxf(acc[r], 0.0f);

        float a2[4];
#pragma unroll
        for (int r = 0; r < 4; ++r) a2[r] = sbh1[j2];
#pragma unroll 4
        for (int k = 0; k < 64; ++k) {
            float w = sWh1[k * 32 + j2];
#pragma unroll
            for (int r = 0; r < 4; ++r) a2[r] += rdlane(h2[r], k) * w;
        }

        float part[4];
#pragma unroll
        for (int r = 0; r < 4; ++r) part[r] = fmaxf(a2[r], 0.0f) * sWh2[j2];
#pragma unroll
        for (int r = 0; r < 4; ++r) {
            float s = part[r];
            s += __shfl_xor(s, 1);
            s += __shfl_xor(s, 2);
            s += __shfl_xor(s, 4);
            s += __shfl_xor(s, 8);
            s += __shfl_xor(s, 16);
            s += __shfl_xor(s, 32);
            part[r] = 0.5f * s + sbh2;  // lanes j2 and j2+32 double-count
        }
        if (lane < 4) {
            int row = base + lane;
            if (row < N) {
                float v = (lane == 0) ? part[0] : (lane == 1) ? part[1]
                         : (lane == 2) ? part[2] : part[3];
                if (f_out) ((float*)out)[row] = v;
                else       ((unsigned short*)out)[row] = f2b(v);
            }
        }
    }
}

// ---------------------------------------------------------------------------
// Workspace layout (bytes):
//   [0,          25600000)  evt_h  bf16 [200000,64]
//   [25600000,   38400000)  loc_h  bf16 [100000,64]
//   [38400000,   64000000)  msg    f32  [100000,64]
//   [64000000,   64400000)  cnt    f32  [100000]
//   [64400000,   64416384)  Wperm_evt bf16
//   [64416384,   64432768)  Wperm_loc bf16
//   [64432768,   64432832)  flags  int[16]
// ---------------------------------------------------------------------------
extern "C" void kernel_launch(void* const* d_in, const int* in_sizes, int n_in,
                              void* d_out, int out_size, void* d_ws, size_t ws_size,
                              hipStream_t stream) {
    (void)in_sizes; (void)n_in; (void)out_size; (void)ws_size;
    const void* loc_x = d_in[0];
    const void* evt_x = d_in[1];
    const int*  eidx  = (const int*)d_in[2];
    const void* W_loc = d_in[3];
    const void* b_loc = d_in[4];
    const void* W_evt = d_in[5];
    const void* b_evt = d_in[6];
    const void* W_l   = d_in[7];
    const void* b_l   = d_in[8];
    const void* W_r   = d_in[9];
    const void* W_h1  = d_in[10];
    const void* b_h1  = d_in[11];
    const void* W_h2  = d_in[12];
    const void* b_h2  = d_in[13];

    char* ws = (char*)d_ws;
    unsigned short* evt_h  = (unsigned short*)(ws);
    unsigned short* loc_h  = (unsigned short*)(ws + 25600000);
    float*          msg    = (float*)(ws + 38400000);
    float*          cnt    = (float*)(ws + 64000000);
    unsigned short* wp_evt = (unsigned short*)(ws + 64400000);
    unsigned short* wp_loc = (unsigned short*)(ws + 64416384);
    int*            flags  = (int*)(ws + 64432768);

    detect_kernel<<<1, 64, 0, stream>>>(loc_x, evt_x, eidx,
                                        W_loc, b_loc, W_evt, b_evt,
                                        W_l, b_l, W_r, W_h1, b_h1, W_h2, b_h2,
                                        flags);

    // zero msg + cnt (26,000,000 B = 1,625,000 float4)
    zero_kernel<<<(1625000 + 255) / 256, 256, 0, stream>>>(
        (float4*)(ws + 38400000), 1625000);

    permute_w_kernel<<<4, 256, 0, stream>>>(W_evt, wp_evt, flags, 5);
    permute_w_kernel<<<4, 256, 0, stream>>>(W_loc, wp_loc, flags, 3);

    proj_kernel<<<(N_EVT + 63) / 64, 256, 0, stream>>>(evt_x, wp_evt, b_evt,
                                                       evt_h, N_EVT, flags, 1, 6);
    proj_kernel<<<(N_LOC + 63) / 64, 256, 0, stream>>>(loc_x, wp_loc, b_loc,
                                                       loc_h, N_LOC, flags, 0, 4);

    scatter_kernel<<<(E_CNT * 16) / 256, 256, 0, stream>>>(evt_h, eidx, msg, cnt, flags);

    head_kernel<<<1024, 256, 0, stream>>>(msg, cnt, loc_h,
                                          W_l, b_l, W_r, W_h1, b_h1, W_h2, b_h2,
                                          d_out, N_LOC, flags);
}

// Round 3
// 453.698 us; speedup vs baseline: 2.9060x; 2.9060x over previous
//
#include <hip/hip_runtime.h>

// ---------------------------------------------------------------------------
// HeteroGNN fused pipeline for MI355X (gfx950).
//   loc_h = relu(loc_x @ W_loc + b_loc)          [100000, 64]
//   evt_h = relu(evt_x @ W_evt + b_evt)          [200000, 64]
//   agg   = segment_mean(evt_h[src] -> dst)      [100000, 64]   (CSR gather)
//   h2    = relu(agg @ W_l + b_l + loc_h @ W_r)  [100000, 64]   (MFMA)
//   h1    = relu(h2 @ W_h1 + b_h1)               [100000, 32]   (MFMA)
//   out   = h1 @ W_h2 + b_h2                     [100000]
// R3: atomic scatter (898us, 1.06GB HBM write-through) replaced by
// hist -> exclusive scan -> CSR fill -> gather-mean; head rewritten as MFMA.
// Dtypes (bf16 vs fp32 per tensor, int32/int64 edge_index) runtime-detected.
// ---------------------------------------------------------------------------

#define N_LOC 100000
#define N_EVT 200000
#define E_CNT 1000000
#define NTILES 6250   // N_LOC / 16

typedef __attribute__((ext_vector_type(8))) short short8;   // 8 x bf16
typedef __attribute__((ext_vector_type(4))) float floatx4;  // MFMA C/D frag

__device__ __forceinline__ float b2f(unsigned short u) {
    unsigned int x = ((unsigned int)u) << 16;
    return __builtin_bit_cast(float, x);
}
__device__ __forceinline__ unsigned short f2b(float f) {
    unsigned int x = __builtin_bit_cast(unsigned int, f);
    unsigned int r = (x + 0x7fffu + ((x >> 16) & 1u)) >> 16;  // RNE
    return (unsigned short)r;
}
__device__ __forceinline__ float loadf(const void* p, int f32, size_t i) {
    return f32 ? ((const float*)p)[i] : b2f(((const unsigned short*)p)[i]);
}

// ---------------------------------------------------------------------------
// K_detect: per-tensor dtype detection (1 = fp32). flags[2]: edge_index int64.
// ---------------------------------------------------------------------------
__global__ void detect_kernel(
    const void* t0, const void* t1, const int* eidx,
    const void* t3, const void* t4, const void* t5, const void* t6,
    const void* t7, const void* t8, const void* t9, const void* t10,
    const void* t11, const void* t12, const void* t13, int* flags) {
    const void* ptrs[13] = {t0, t1, t3, t4, t5, t6, t7, t8, t9, t10, t11, t12, t13};
    const int   cnts[13] = {12800000, 25600000, 8192, 64, 8192, 64,
                            4096, 64, 4096, 2048, 32, 32, 1};
    const int   slot[13] = {0, 1, 3, 4, 5, 6, 7, 8, 9, 10, 11, 12, 13};
    int lane = threadIdx.x;
    for (int t = 0; t < 13; ++t) {
        int nsamp = 2 * cnts[t];
        if (nsamp > 1024) nsamp = 1024;
        const unsigned short* h = (const unsigned short*)ptrs[t];
        int susp = 0;
        for (int i = lane; i < nsamp; i += 64) {
            int e = (h[i] >> 7) & 0xFF;
            if (e >= 0x90) susp++;
        }
        for (int d = 1; d < 64; d <<= 1) susp += __shfl_xor(susp, d);
        if (lane == 0) flags[slot[t]] = (susp * 16 >= nsamp) ? 1 : 0;
    }
    int oddnz = 0, evennz = 0;
    for (int i = lane; i < 128; i += 64) {
        if (eidx[2 * i] != 0) evennz++;
        if (eidx[2 * i + 1] != 0) oddnz++;
    }
    for (int d = 1; d < 64; d <<= 1) {
        oddnz += __shfl_xor(oddnz, d);
        evennz += __shfl_xor(evennz, d);
    }
    if (lane == 0) flags[2] = (oddnz == 0 && evennz > 32) ? 1 : 0;
}

// ---------------------------------------------------------------------------
// K_zero: zero an int/float region (graph-capture-safe).
// ---------------------------------------------------------------------------
__global__ __launch_bounds__(256) void zero_kernel(float4* p, int n4) {
    int i = blockIdx.x * 256 + threadIdx.x;
    if (i < n4) p[i] = make_float4(0.f, 0.f, 0.f, 0.f);
}

// ---------------------------------------------------------------------------
// K0: permute W [K,N] row-major into MFMA B-fragment order (bf16 out).
// frag f = t*(K/32)+kk; lane l holds B[k=kk*32+(l>>4)*8+j][n=t*16+(l&15)].
// ---------------------------------------------------------------------------
__global__ __launch_bounds__(256) void permute_w_kernel(
    const void* W, unsigned short* Wp, const int* flags, int slot,
    int K, int N) {
    int f32 = flags[slot];
    int nk = K >> 5;
    int frags = (N >> 4) * nk;
    int idx = blockIdx.x * 256 + threadIdx.x;
    if (idx >= frags * 64) return;
    int f    = idx >> 6;
    int lane = idx & 63;
    int t  = f / nk;
    int kk = f % nk;
    int n  = t * 16 + (lane & 15);
    int k0 = kk * 32 + (lane >> 4) * 8;
    unsigned short tmp[8];
#pragma unroll
    for (int j = 0; j < 8; ++j) {
        size_t src = (size_t)(k0 + j) * N + n;
        tmp[j] = f32 ? f2b(((const float*)W)[src])
                     : ((const unsigned short*)W)[src];
    }
#pragma unroll
    for (int j = 0; j < 8; ++j) Wp[(size_t)idx * 8 + j] = tmp[j];
}

// ---------------------------------------------------------------------------
// K1: Y[M,64] = relu(X[M,128] @ W[128,64] + b), MFMA 16x16x32, bf16 out.
// ---------------------------------------------------------------------------
__global__ __launch_bounds__(256) void proj_kernel(
    const void* __restrict__ X,
    const unsigned short* __restrict__ Wp,
    const void* __restrict__ bias,
    unsigned short* __restrict__ Y, int M,
    const int* __restrict__ flags, int sx, int sb) {
    int fx = flags[sx], fb = flags[sb];
    int tid  = threadIdx.x;
    int lane = tid & 63;
    int wv   = tid >> 6;
    int l15  = lane & 15;
    int quad = lane >> 4;
    int row_base = blockIdx.x * 64 + wv * 16;

    short8 b[16];
#pragma unroll
    for (int f = 0; f < 16; ++f)
        b[f] = *reinterpret_cast<const short8*>(Wp + ((size_t)(f * 64 + lane)) * 8);

    int m = row_base + l15;
    short8 a[4];
#pragma unroll
    for (int kk = 0; kk < 4; ++kk) a[kk] = (short8)0;
    if (m < M) {
        if (fx) {
            const float* xr = (const float*)X + (size_t)m * 128 + quad * 8;
#pragma unroll
            for (int kk = 0; kk < 4; ++kk) {
                float4 p0 = *reinterpret_cast<const float4*>(xr + kk * 32);
                float4 p1 = *reinterpret_cast<const float4*>(xr + kk * 32 + 4);
                short8 v;
                v[0] = (short)f2b(p0.x); v[1] = (short)f2b(p0.y);
                v[2] = (short)f2b(p0.z); v[3] = (short)f2b(p0.w);
                v[4] = (short)f2b(p1.x); v[5] = (short)f2b(p1.y);
                v[6] = (short)f2b(p1.z); v[7] = (short)f2b(p1.w);
                a[kk] = v;
            }
        } else {
            const unsigned short* xr = (const unsigned short*)X + (size_t)m * 128 + quad * 8;
#pragma unroll
            for (int kk = 0; kk < 4; ++kk)
                a[kk] = *reinterpret_cast<const short8*>(xr + kk * 32);
        }
    }

    floatx4 acc[4];
#pragma unroll
    for (int t = 0; t < 4; ++t) acc[t] = (floatx4)0.0f;
#pragma unroll
    for (int kk = 0; kk < 4; ++kk) {
#pragma unroll
        for (int t = 0; t < 4; ++t)
            acc[t] = __builtin_amdgcn_mfma_f32_16x16x32_bf16(
                a[kk], b[t * 4 + kk], acc[t], 0, 0, 0);
    }

#pragma unroll
    for (int t = 0; t < 4; ++t) {
        float bv = loadf(bias, fb, t * 16 + l15);
#pragma unroll
        for (int r = 0; r < 4; ++r) {
            int row = row_base + quad * 4 + r;
            if (row < M) {
                float v = acc[t][r] + bv;
                v = v > 0.0f ? v : 0.0f;
                Y[(size_t)row * 64 + t * 16 + l15] = f2b(v);
            }
        }
    }
}

// ---------------------------------------------------------------------------
// K2a: histogram of destination degrees.
// ---------------------------------------------------------------------------
__global__ __launch_bounds__(256) void hist_kernel(
    const int* __restrict__ eidx, int* __restrict__ cnt,
    const int* __restrict__ flags) {
    int e = blockIdx.x * 256 + threadIdx.x;
    if (e >= E_CNT) return;
    int dst = flags[2] ? (int)((const long long*)eidx)[E_CNT + e]
                       : eidx[E_CNT + e];
    if ((unsigned)dst < (unsigned)N_LOC) atomicAdd(cnt + dst, 1);
}

// ---------------------------------------------------------------------------
// K2b: per-1024-chunk sums of cnt.
// ---------------------------------------------------------------------------
__global__ __launch_bounds__(256) void scan_sums_kernel(
    const int* __restrict__ cnt, int* __restrict__ bsum, int n) {
    __shared__ int ws[4];
    int b = blockIdx.x, tid = threadIdx.x;
    int base = b * 1024 + tid * 4;
    int s = 0;
#pragma unroll
    for (int j = 0; j < 4; ++j) {
        int i = base + j;
        if (i < n) s += cnt[i];
    }
    for (int d = 1; d < 64; d <<= 1) s += __shfl_xor(s, d);
    if ((tid & 63) == 0) ws[tid >> 6] = s;
    __syncthreads();
    if (tid == 0) bsum[b] = ws[0] + ws[1] + ws[2] + ws[3];
}

// ---------------------------------------------------------------------------
// K2c: exclusive scan of block sums (nb <= 128), single block of 128 threads.
// ---------------------------------------------------------------------------
__global__ void scan_bsum_kernel(int* bsum, int nb) {
    __shared__ int sh[128];
    int t = threadIdx.x;
    int v = (t < nb) ? bsum[t] : 0;
    sh[t] = v;
    __syncthreads();
    for (int d = 1; d < 128; d <<= 1) {
        int x = (t >= d) ? sh[t - d] : 0;
        __syncthreads();
        sh[t] += x;
        __syncthreads();
    }
    if (t < nb) bsum[t] = sh[t] - v;   // exclusive
}

// ---------------------------------------------------------------------------
// K2d: write rowptr (exclusive prefix) + wofs copy; last thread writes total.
// ---------------------------------------------------------------------------
__global__ __launch_bounds__(256) void scan_write_kernel(
    const int* __restrict__ cnt, const int* __restrict__ bsum,
    int* __restrict__ rowptr, int* __restrict__ wofs, int n) {
    __shared__ int wsum[4];
    int b = blockIdx.x, tid = threadIdx.x, lane = tid & 63, wv = tid >> 6;
    int base = b * 1024 + tid * 4;
    int c[4];
    int tot = 0;
#pragma unroll
    for (int j = 0; j < 4; ++j) {
        int i = base + j;
        c[j] = (i < n) ? cnt[i] : 0;
        tot += c[j];
    }
    int sc = tot;  // inclusive wave scan
    for (int d = 1; d < 64; d <<= 1) {
        int x = __shfl_up(sc, d);
        if (lane >= d) sc += x;
    }
    if (lane == 63) wsum[wv] = sc;
    __syncthreads();
    int woff = 0;
    for (int w = 0; w < wv; ++w) woff += wsum[w];
    int excl = bsum[b] + woff + (sc - tot);
    int run = excl;
#pragma unroll
    for (int j = 0; j < 4; ++j) {
        int i = base + j;
        if (i < n) { rowptr[i] = run; wofs[i] = run; }
        run += c[j];
    }
    if (b == (int)gridDim.x - 1 && tid == 255) rowptr[n] = run;
}

// ---------------------------------------------------------------------------
// K2e: scatter edge src ids into CSR order.
// ---------------------------------------------------------------------------
__global__ __launch_bounds__(256) void fill_kernel(
    const int* __restrict__ eidx, int* __restrict__ wofs,
    int* __restrict__ csr, const int* __restrict__ flags) {
    int e = blockIdx.x * 256 + threadIdx.x;
    if (e >= E_CNT) return;
    int src, dst;
    if (flags[2]) {
        const long long* p = (const long long*)eidx;
        src = (int)p[e];
        dst = (int)p[E_CNT + e];
    } else {
        src = eidx[e];
        dst = eidx[E_CNT + e];
    }
    if ((unsigned)dst >= (unsigned)N_LOC || (unsigned)src >= (unsigned)N_EVT) return;
    int p = atomicAdd(wofs + dst, 1);
    csr[p] = src;
}

// ---------------------------------------------------------------------------
// K3: gather-mean. One wave per location row; lane = column. 128B row reads
// of evt_h (fits L2/L3). agg written bf16.
// ---------------------------------------------------------------------------
__global__ __launch_bounds__(256) void aggregate_kernel(
    const unsigned short* __restrict__ evt_h,
    const int* __restrict__ rowptr, const int* __restrict__ csr,
    unsigned short* __restrict__ agg, int N) {
    int wid  = (blockIdx.x * 256 + threadIdx.x) >> 6;
    int lane = threadIdx.x & 63;
    if (wid >= N) return;
    int e0 = rowptr[wid], e1 = rowptr[wid + 1];
    float acc = 0.0f;
    int j = e0;
    for (; j + 3 < e1; j += 4) {
        int s0 = csr[j], s1 = csr[j + 1], s2 = csr[j + 2], s3 = csr[j + 3];
        float v0 = b2f(evt_h[(size_t)s0 * 64 + lane]);
        float v1 = b2f(evt_h[(size_t)s1 * 64 + lane]);
        float v2 = b2f(evt_h[(size_t)s2 * 64 + lane]);
        float v3 = b2f(evt_h[(size_t)s3 * 64 + lane]);
        acc += v0 + v1 + v2 + v3;
    }
    for (; j < e1; ++j) {
        int s = csr[j];
        acc += b2f(evt_h[(size_t)s * 64 + lane]);
    }
    float inv = (e1 > e0) ? 1.0f / (float)(e1 - e0) : 0.0f;
    agg[(size_t)wid * 64 + lane] = f2b(acc * inv);
}

// ---------------------------------------------------------------------------
// K4: fused SAGE + head via MFMA. One wave = 16-row tile (no block barrier,
// LDS is wave-private -> early return safe).
//   h2 = relu(agg@W_l + loc_h@W_r + b_l)   [16x64]  (4 t-tiles x 2 k-chunks x 2)
//   LDS transpose C-layout -> A-layout
//   h1 = relu(h2@W_h1 + b_h1)              [16x32]
//   out = relu(h1)... no: out = h1relu @ W_h2 + b_h2 -> row-sum reduce
// ---------------------------------------------------------------------------
__global__ __launch_bounds__(256) void head_kernel(
    const unsigned short* __restrict__ agg,
    const unsigned short* __restrict__ loc_h,
    const unsigned short* __restrict__ wp_l,
    const unsigned short* __restrict__ wp_r,
    const unsigned short* __restrict__ wp_h1,
    const void* __restrict__ bl, const void* __restrict__ bh1,
    const void* __restrict__ wh2, const void* __restrict__ bh2,
    void* __restrict__ out, const int* __restrict__ flags) {
    __shared__ unsigned short h2s[4][16 * 64];
    int tid = threadIdx.x, lane = tid & 63, wv = tid >> 6;
    int tile = blockIdx.x * 4 + wv;
    if (tile >= NTILES) return;
    int l15 = lane & 15, quad = lane >> 4;
    int fbl = flags[8], fbh1 = flags[11], fwh2 = flags[12], fbh2 = flags[13];
    int fout = flags[0];
    int base = tile * 16;

    short8 bwl[8], bwr[8], bw1[4];
#pragma unroll
    for (int f = 0; f < 8; ++f) {
        bwl[f] = *reinterpret_cast<const short8*>(wp_l + ((size_t)(f * 64 + lane)) * 8);
        bwr[f] = *reinterpret_cast<const short8*>(wp_r + ((size_t)(f * 64 + lane)) * 8);
    }
#pragma unroll
    for (int f = 0; f < 4; ++f)
        bw1[f] = *reinterpret_cast<const short8*>(wp_h1 + ((size_t)(f * 64 + lane)) * 8);

    short8 aA[2], aL[2];
#pragma unroll
    for (int kk = 0; kk < 2; ++kk) {
        aA[kk] = *reinterpret_cast<const short8*>(
            agg + (size_t)(base + l15) * 64 + kk * 32 + quad * 8);
        aL[kk] = *reinterpret_cast<const short8*>(
            loc_h + (size_t)(base + l15) * 64 + kk * 32 + quad * 8);
    }

    floatx4 acc[4];
#pragma unroll
    for (int t = 0; t < 4; ++t) acc[t] = (floatx4)0.0f;
#pragma unroll
    for (int kk = 0; kk < 2; ++kk) {
#pragma unroll
        for (int t = 0; t < 4; ++t) {
            acc[t] = __builtin_amdgcn_mfma_f32_16x16x32_bf16(
                aA[kk], bwl[t * 2 + kk], acc[t], 0, 0, 0);
            acc[t] = __builtin_amdgcn_mfma_f32_16x16x32_bf16(
                aL[kk], bwr[t * 2 + kk], acc[t], 0, 0, 0);
        }
    }

    // h2 -> LDS (row-major [16][64], bf16), C-layout: row=quad*4+r, col=t*16+l15
#pragma unroll
    for (int t = 0; t < 4; ++t) {
        float bb = loadf(bl, fbl, t * 16 + l15);
#pragma unroll
        for (int r = 0; r < 4; ++r) {
            float v = acc[t][r] + bb;
            v = v > 0.0f ? v : 0.0f;
            h2s[wv][(quad * 4 + r) * 64 + t * 16 + l15] = f2b(v);
        }
    }
    // wave-private LDS round-trip: compiler inserts lgkmcnt wait (same array)
    short8 aH[2];
#pragma unroll
    for (int kk = 0; kk < 2; ++kk)
        aH[kk] = *reinterpret_cast<const short8*>(
            &h2s[wv][l15 * 64 + kk * 32 + quad * 8]);

    floatx4 a1[2];
#pragma unroll
    for (int t = 0; t < 2; ++t) a1[t] = (floatx4)0.0f;
#pragma unroll
    for (int kk = 0; kk < 2; ++kk)
#pragma unroll
        for (int t = 0; t < 2; ++t)
            a1[t] = __builtin_amdgcn_mfma_f32_16x16x32_bf16(
                aH[kk], bw1[t * 2 + kk], a1[t], 0, 0, 0);

    float s[4] = {0.f, 0.f, 0.f, 0.f};
#pragma unroll
    for (int t = 0; t < 2; ++t) {
        float bb = loadf(bh1, fbh1, t * 16 + l15);
        float w2 = loadf(wh2, fwh2, t * 16 + l15);
#pragma unroll
        for (int r = 0; r < 4; ++r) {
            float v = a1[t][r] + bb;
            v = v > 0.0f ? v : 0.0f;
            s[r] += v * w2;
        }
    }
#pragma unroll
    for (int r = 0; r < 4; ++r) {
        s[r] += __shfl_xor(s[r], 1);
        s[r] += __shfl_xor(s[r], 2);
        s[r] += __shfl_xor(s[r], 4);
        s[r] += __shfl_xor(s[r], 8);
    }
    float bb2 = loadf(bh2, fbh2, 0);
#pragma unroll
    for (int r = 0; r < 4; ++r) {
        if (l15 == r) {
            int row = base + quad * 4 + r;
            float v = s[r] + bb2;
            if (fout) ((float*)out)[row] = v;
            else      ((unsigned short*)out)[row] = f2b(v);
        }
    }
}

// ---------------------------------------------------------------------------
// Workspace layout (bytes), total < 43.7 MB:
//   0:          evt_h   bf16 [200000,64]   (25,600,000)
//   25600000:   loc_h   bf16 [100000,64]   (12,800,000)
//   38400000:   agg     bf16 [100000,64]   ... wait, reuse: csr first
// Layout:
//   0:          evt_h    (25,600,000)
//   25600000:   loc_h    (12,800,000)
//   38400000:   csr_src  int [1M]      (4,000,000)
//   42400000:   cnt      int [100000]  (400,000)
//   42800000:   rowptr   int [100001]  (400,016)
//   43200016:   wofs     int [100000]  (400,000)
//   43600016:   bsum     int [<=1024]  (4,096)
//   43604112:   agg      bf16 [100000,64] (12,800,000)
//   56404112:   wp_evt   (16,384)
//   56420496:   wp_loc   (16,384)
//   56436880:   wp_l     (8,192)
//   56445072:   wp_r     (8,192)
//   56453264:   wp_h1    (4,096)
//   56457360:   flags    int[16]
// ---------------------------------------------------------------------------
extern "C" void kernel_launch(void* const* d_in, const int* in_sizes, int n_in,
                              void* d_out, int out_size, void* d_ws, size_t ws_size,
                              hipStream_t stream) {
    (void)in_sizes; (void)n_in; (void)out_size; (void)ws_size;
    const void* loc_x = d_in[0];
    const void* evt_x = d_in[1];
    const int*  eidx  = (const int*)d_in[2];
    const void* W_loc = d_in[3];
    const void* b_loc = d_in[4];
    const void* W_evt = d_in[5];
    const void* b_evt = d_in[6];
    const void* W_l   = d_in[7];
    const void* b_l   = d_in[8];
    const void* W_r   = d_in[9];
    const void* W_h1  = d_in[10];
    const void* b_h1  = d_in[11];
    const void* W_h2  = d_in[12];
    const void* b_h2  = d_in[13];

    char* ws = (char*)d_ws;
    unsigned short* evt_h  = (unsigned short*)(ws);
    unsigned short* loc_h  = (unsigned short*)(ws + 25600000);
    int*            csr    = (int*)(ws + 38400000);
    int*            cnt    = (int*)(ws + 42400000);
    int*            rowptr = (int*)(ws + 42800000);
    int*            wofs   = (int*)(ws + 43200016);
    int*            bsum   = (int*)(ws + 43600016);
    unsigned short* agg    = (unsigned short*)(ws + 43604112);
    unsigned short* wp_evt = (unsigned short*)(ws + 56404112);
    unsigned short* wp_loc = (unsigned short*)(ws + 56420496);
    unsigned short* wp_l   = (unsigned short*)(ws + 56436880);
    unsigned short* wp_r   = (unsigned short*)(ws + 56445072);
    unsigned short* wp_h1  = (unsigned short*)(ws + 56453264);
    int*            flags  = (int*)(ws + 56457360);

    detect_kernel<<<1, 64, 0, stream>>>(loc_x, evt_x, eidx,
                                        W_loc, b_loc, W_evt, b_evt,
                                        W_l, b_l, W_r, W_h1, b_h1, W_h2, b_h2,
                                        flags);

    // zero cnt (400,000 B = 25,000 float4)
    zero_kernel<<<98, 256, 0, stream>>>((float4*)(ws + 42400000), 25000);

    permute_w_kernel<<<4, 256, 0, stream>>>(W_evt, wp_evt, flags, 5, 128, 64);
    permute_w_kernel<<<4, 256, 0, stream>>>(W_loc, wp_loc, flags, 3, 128, 64);
    permute_w_kernel<<<2, 256, 0, stream>>>(W_l,   wp_l,   flags, 7, 64, 64);
    permute_w_kernel<<<2, 256, 0, stream>>>(W_r,   wp_r,   flags, 9, 64, 64);
    permute_w_kernel<<<1, 256, 0, stream>>>(W_h1,  wp_h1,  flags, 10, 64, 32);

    proj_kernel<<<(N_EVT + 63) / 64, 256, 0, stream>>>(evt_x, wp_evt, b_evt,
                                                       evt_h, N_EVT, flags, 1, 6);
    proj_kernel<<<(N_LOC + 63) / 64, 256, 0, stream>>>(loc_x, wp_loc, b_loc,
                                                       loc_h, N_LOC, flags, 0, 4);

    hist_kernel<<<(E_CNT + 255) / 256, 256, 0, stream>>>(eidx, cnt, flags);
    scan_sums_kernel<<<98, 256, 0, stream>>>(cnt, bsum, N_LOC);
    scan_bsum_kernel<<<1, 128, 0, stream>>>(bsum, 98);
    scan_write_kernel<<<98, 256, 0, stream>>>(cnt, bsum, rowptr, wofs, N_LOC);
    fill_kernel<<<(E_CNT + 255) / 256, 256, 0, stream>>>(eidx, wofs, csr, flags);

    aggregate_kernel<<<(N_LOC + 3) / 4, 256, 0, stream>>>(evt_h, rowptr, csr,
                                                          agg, N_LOC);

    head_kernel<<<(NTILES + 3) / 4, 256, 0, stream>>>(agg, loc_h,
                                                      wp_l, wp_r, wp_h1,
                                                      b_l, b_h1, W_h2, b_h2,
                                                      d_out, flags);
}

// Round 4
// 442.742 us; speedup vs baseline: 2.9779x; 1.0247x over previous
//
#include <hip/hip_runtime.h>

// ---------------------------------------------------------------------------
// HeteroGNN fused pipeline for MI355X (gfx950).
//   loc_h = relu(loc_x @ W_loc + b_loc)          [100000, 64]
//   evt_h = relu(evt_x @ W_evt + b_evt)          [200000, 64]
//   agg   = segment_mean(evt_h[src] -> dst)      (CSR gather, fused into head)
//   h2    = relu(agg @ W_l + b_l + loc_h @ W_r)  (MFMA)
//   h1    = relu(h2 @ W_h1 + b_h1)               (MFMA)
//   out   = h1 @ W_h2 + b_h2                     [100000]
// R4: detect parallelized (was single-wave latency-bound), cnt-zero fused into
// detect, 5 permutes fused to 1 launch, aggregate fused into head kernel.
// Launches 17 -> 10.
// ---------------------------------------------------------------------------

#define N_LOC 100000
#define N_EVT 200000
#define E_CNT 1000000
#define NTILES 6250   // N_LOC / 16

typedef __attribute__((ext_vector_type(8))) short short8;   // 8 x bf16
typedef __attribute__((ext_vector_type(4))) float floatx4;  // MFMA C/D frag

__device__ __forceinline__ float b2f(unsigned short u) {
    unsigned int x = ((unsigned int)u) << 16;
    return __builtin_bit_cast(float, x);
}
__device__ __forceinline__ unsigned short f2b(float f) {
    unsigned int x = __builtin_bit_cast(unsigned int, f);
    unsigned int r = (x + 0x7fffu + ((x >> 16) & 1u)) >> 16;  // RNE
    return (unsigned short)r;
}
__device__ __forceinline__ float loadf(const void* p, int f32, size_t i) {
    return f32 ? ((const float*)p)[i] : b2f(((const unsigned short*)p)[i]);
}

// ---------------------------------------------------------------------------
// K_detect+zero: blocks 0..12 probe float-tensor dtypes (1 = fp32),
// block 13 probes edge_index int32/int64, blocks 14..111 zero cnt.
// ---------------------------------------------------------------------------
__global__ __launch_bounds__(256) void detect_zero_kernel(
    const void* t0, const void* t1, const int* eidx,
    const void* t3, const void* t4, const void* t5, const void* t6,
    const void* t7, const void* t8, const void* t9, const void* t10,
    const void* t11, const void* t12, const void* t13,
    int* flags, int4* cnt4) {
    int b = blockIdx.x, tid = threadIdx.x;
    if (b >= 14) {
        int i = (b - 14) * 256 + tid;
        if (i < 25000) cnt4[i] = make_int4(0, 0, 0, 0);
        return;
    }
    __shared__ int s0, s1;
    if (tid == 0) { s0 = 0; s1 = 0; }
    __syncthreads();
    if (b == 13) {   // edge_index: int64 => all odd 32-bit words zero
        if (tid < 128) {
            if (eidx[2 * tid] != 0) atomicAdd(&s0, 1);
            if (eidx[2 * tid + 1] != 0) atomicAdd(&s1, 1);
        }
        __syncthreads();
        if (tid == 0) flags[2] = (s1 == 0 && s0 > 32) ? 1 : 0;
        return;
    }
    const void* ptrs[13] = {t0, t1, t3, t4, t5, t6, t7, t8, t9, t10, t11, t12, t13};
    const int   cnts[13] = {12800000, 25600000, 8192, 64, 8192, 64,
                            4096, 64, 4096, 2048, 32, 32, 1};
    const int   slot[13] = {0, 1, 3, 4, 5, 6, 7, 8, 9, 10, 11, 12, 13};
    int nsamp = 2 * cnts[b];
    if (nsamp > 1024) nsamp = 1024;
    const unsigned short* h = (const unsigned short*)ptrs[b];
    int susp = 0;
    for (int i = tid; i < nsamp; i += 256) {
        int e = (h[i] >> 7) & 0xFF;
        if (e >= 0x90) susp++;
    }
    if (susp) atomicAdd(&s0, susp);
    __syncthreads();
    if (tid == 0) flags[slot[b]] = (s0 * 16 >= nsamp) ? 1 : 0;
}

// ---------------------------------------------------------------------------
// K0: all 5 weight permutes in one launch (13 blocks).
// frag f = t*(K/32)+kk; lane l holds B[k=kk*32+(l>>4)*8+j][n=t*16+(l&15)].
// wp_all element offsets: evt 0, loc 8192, W_l 16384, W_r 20480, W_h1 24576.
// ---------------------------------------------------------------------------
__global__ __launch_bounds__(256) void permute_all_kernel(
    const void* W_evt, const void* W_loc, const void* W_l, const void* W_r,
    const void* W_h1, unsigned short* __restrict__ wp_all,
    const int* __restrict__ flags) {
    int b = blockIdx.x, tid = threadIdx.x;
    const void* W; int K, N, slot, bstart, off;
    if (b < 4)       { W = W_evt; K = 128; N = 64; slot = 5;  bstart = 0;  off = 0; }
    else if (b < 8)  { W = W_loc; K = 128; N = 64; slot = 3;  bstart = 4;  off = 8192; }
    else if (b < 10) { W = W_l;   K = 64;  N = 64; slot = 7;  bstart = 8;  off = 16384; }
    else if (b < 12) { W = W_r;   K = 64;  N = 64; slot = 9;  bstart = 10; off = 20480; }
    else             { W = W_h1;  K = 64;  N = 32; slot = 10; bstart = 12; off = 24576; }
    int f32 = flags[slot];
    int idx  = (b - bstart) * 256 + tid;
    int nk   = K >> 5;
    int f    = idx >> 6;
    int lane = idx & 63;
    int t  = f / nk;
    int kk = f - t * nk;
    int n  = t * 16 + (lane & 15);
    int k0 = kk * 32 + (lane >> 4) * 8;
    unsigned short tmp[8];
#pragma unroll
    for (int j = 0; j < 8; ++j) {
        size_t src = (size_t)(k0 + j) * N + n;
        tmp[j] = f32 ? f2b(((const float*)W)[src])
                     : ((const unsigned short*)W)[src];
    }
#pragma unroll
    for (int j = 0; j < 8; ++j) wp_all[(size_t)off + (size_t)idx * 8 + j] = tmp[j];
}

// ---------------------------------------------------------------------------
// K1: Y[M,64] = relu(X[M,128] @ W[128,64] + b), MFMA 16x16x32, bf16 out.
// ---------------------------------------------------------------------------
__global__ __launch_bounds__(256) void proj_kernel(
    const void* __restrict__ X,
    const unsigned short* __restrict__ Wp,
    const void* __restrict__ bias,
    unsigned short* __restrict__ Y, int M,
    const int* __restrict__ flags, int sx, int sb) {
    int fx = flags[sx], fb = flags[sb];
    int tid  = threadIdx.x;
    int lane = tid & 63;
    int wv   = tid >> 6;
    int l15  = lane & 15;
    int quad = lane >> 4;
    int row_base = blockIdx.x * 64 + wv * 16;

    short8 b[16];
#pragma unroll
    for (int f = 0; f < 16; ++f)
        b[f] = *reinterpret_cast<const short8*>(Wp + ((size_t)(f * 64 + lane)) * 8);

    int m = row_base + l15;
    short8 a[4];
#pragma unroll
    for (int kk = 0; kk < 4; ++kk) a[kk] = (short8)0;
    if (m < M) {
        if (fx) {
            const float* xr = (const float*)X + (size_t)m * 128 + quad * 8;
#pragma unroll
            for (int kk = 0; kk < 4; ++kk) {
                float4 p0 = *reinterpret_cast<const float4*>(xr + kk * 32);
                float4 p1 = *reinterpret_cast<const float4*>(xr + kk * 32 + 4);
                short8 v;
                v[0] = (short)f2b(p0.x); v[1] = (short)f2b(p0.y);
                v[2] = (short)f2b(p0.z); v[3] = (short)f2b(p0.w);
                v[4] = (short)f2b(p1.x); v[5] = (short)f2b(p1.y);
                v[6] = (short)f2b(p1.z); v[7] = (short)f2b(p1.w);
                a[kk] = v;
            }
        } else {
            const unsigned short* xr = (const unsigned short*)X + (size_t)m * 128 + quad * 8;
#pragma unroll
            for (int kk = 0; kk < 4; ++kk)
                a[kk] = *reinterpret_cast<const short8*>(xr + kk * 32);
        }
    }

    floatx4 acc[4];
#pragma unroll
    for (int t = 0; t < 4; ++t) acc[t] = (floatx4)0.0f;
#pragma unroll
    for (int kk = 0; kk < 4; ++kk) {
#pragma unroll
        for (int t = 0; t < 4; ++t)
            acc[t] = __builtin_amdgcn_mfma_f32_16x16x32_bf16(
                a[kk], b[t * 4 + kk], acc[t], 0, 0, 0);
    }

#pragma unroll
    for (int t = 0; t < 4; ++t) {
        float bv = loadf(bias, fb, t * 16 + l15);
#pragma unroll
        for (int r = 0; r < 4; ++r) {
            int row = row_base + quad * 4 + r;
            if (row < M) {
                float v = acc[t][r] + bv;
                v = v > 0.0f ? v : 0.0f;
                Y[(size_t)row * 64 + t * 16 + l15] = f2b(v);
            }
        }
    }
}

// ---------------------------------------------------------------------------
// K2a: histogram of destination degrees.
// ---------------------------------------------------------------------------
__global__ __launch_bounds__(256) void hist_kernel(
    const int* __restrict__ eidx, int* __restrict__ cnt,
    const int* __restrict__ flags) {
    int e = blockIdx.x * 256 + threadIdx.x;
    if (e >= E_CNT) return;
    int dst = flags[2] ? (int)((const long long*)eidx)[E_CNT + e]
                       : eidx[E_CNT + e];
    if ((unsigned)dst < (unsigned)N_LOC) atomicAdd(cnt + dst, 1);
}

// ---------------------------------------------------------------------------
// K2b: per-1024-chunk sums of cnt.
// ---------------------------------------------------------------------------
__global__ __launch_bounds__(256) void scan_sums_kernel(
    const int* __restrict__ cnt, int* __restrict__ bsum, int n) {
    __shared__ int ws[4];
    int b = blockIdx.x, tid = threadIdx.x;
    int base = b * 1024 + tid * 4;
    int s = 0;
#pragma unroll
    for (int j = 0; j < 4; ++j) {
        int i = base + j;
        if (i < n) s += cnt[i];
    }
    for (int d = 1; d < 64; d <<= 1) s += __shfl_xor(s, d);
    if ((tid & 63) == 0) ws[tid >> 6] = s;
    __syncthreads();
    if (tid == 0) bsum[b] = ws[0] + ws[1] + ws[2] + ws[3];
}

// ---------------------------------------------------------------------------
// K2c: exclusive scan of block sums (nb <= 128), single block of 128 threads.
// ---------------------------------------------------------------------------
__global__ void scan_bsum_kernel(int* bsum, int nb) {
    __shared__ int sh[128];
    int t = threadIdx.x;
    int v = (t < nb) ? bsum[t] : 0;
    sh[t] = v;
    __syncthreads();
    for (int d = 1; d < 128; d <<= 1) {
        int x = (t >= d) ? sh[t - d] : 0;
        __syncthreads();
        sh[t] += x;
        __syncthreads();
    }
    if (t < nb) bsum[t] = sh[t] - v;   // exclusive
}

// ---------------------------------------------------------------------------
// K2d: write rowptr (exclusive prefix) + wofs copy; last thread writes total.
// ---------------------------------------------------------------------------
__global__ __launch_bounds__(256) void scan_write_kernel(
    const int* __restrict__ cnt, const int* __restrict__ bsum,
    int* __restrict__ rowptr, int* __restrict__ wofs, int n) {
    __shared__ int wsum[4];
    int b = blockIdx.x, tid = threadIdx.x, lane = tid & 63, wv = tid >> 6;
    int base = b * 1024 + tid * 4;
    int c[4];
    int tot = 0;
#pragma unroll
    for (int j = 0; j < 4; ++j) {
        int i = base + j;
        c[j] = (i < n) ? cnt[i] : 0;
        tot += c[j];
    }
    int sc = tot;  // inclusive wave scan
    for (int d = 1; d < 64; d <<= 1) {
        int x = __shfl_up(sc, d);
        if (lane >= d) sc += x;
    }
    if (lane == 63) wsum[wv] = sc;
    __syncthreads();
    int woff = 0;
    for (int w = 0; w < wv; ++w) woff += wsum[w];
    int excl = bsum[b] + woff + (sc - tot);
    int run = excl;
#pragma unroll
    for (int j = 0; j < 4; ++j) {
        int i = base + j;
        if (i < n) { rowptr[i] = run; wofs[i] = run; }
        run += c[j];
    }
    if (b == (int)gridDim.x - 1 && tid == 255) rowptr[n] = run;
}

// ---------------------------------------------------------------------------
// K2e: scatter edge src ids into CSR order.
// ---------------------------------------------------------------------------
__global__ __launch_bounds__(256) void fill_kernel(
    const int* __restrict__ eidx, int* __restrict__ wofs,
    int* __restrict__ csr, const int* __restrict__ flags) {
    int e = blockIdx.x * 256 + threadIdx.x;
    if (e >= E_CNT) return;
    int src, dst;
    if (flags[2]) {
        const long long* p = (const long long*)eidx;
        src = (int)p[e];
        dst = (int)p[E_CNT + e];
    } else {
        src = eidx[e];
        dst = eidx[E_CNT + e];
    }
    if ((unsigned)dst >= (unsigned)N_LOC || (unsigned)src >= (unsigned)N_EVT) return;
    int p = atomicAdd(wofs + dst, 1);
    csr[p] = src;
}

// ---------------------------------------------------------------------------
// K3: fused gather-mean + SAGE + head. One wave = 16-row tile; phase 1 gathers
// the tile's segment means into wave-private LDS; phase 2 runs the MFMA head.
// No block barrier -> early return safe.
// ---------------------------------------------------------------------------
__global__ __launch_bounds__(256) void gather_head_kernel(
    const unsigned short* __restrict__ evt_h,
    const unsigned short* __restrict__ loc_h,
    const int* __restrict__ rowptr, const int* __restrict__ csr,
    const unsigned short* __restrict__ wp_l,
    const unsigned short* __restrict__ wp_r,
    const unsigned short* __restrict__ wp_h1,
    const void* __restrict__ bl, const void* __restrict__ bh1,
    const void* __restrict__ wh2, const void* __restrict__ bh2,
    void* __restrict__ out, const int* __restrict__ flags) {
    __shared__ unsigned short tileS[4][16 * 64];  // agg tile (bf16)
    __shared__ unsigned short h2s[4][16 * 64];    // h2 transpose buffer
    int tid = threadIdx.x, lane = tid & 63, wv = tid >> 6;
    int tile = blockIdx.x * 4 + wv;
    if (tile >= NTILES) return;
    int l15 = lane & 15, quad = lane >> 4;
    int fbl = flags[8], fbh1 = flags[11], fwh2 = flags[12], fbh2 = flags[13];
    int fout = flags[0];
    int base = tile * 16;

    // B fragments (prefetched; independent of phase 1)
    short8 bwl[8], bwr[8], bw1[4];
#pragma unroll
    for (int f = 0; f < 8; ++f) {
        bwl[f] = *reinterpret_cast<const short8*>(wp_l + ((size_t)(f * 64 + lane)) * 8);
        bwr[f] = *reinterpret_cast<const short8*>(wp_r + ((size_t)(f * 64 + lane)) * 8);
    }
#pragma unroll
    for (int f = 0; f < 4; ++f)
        bw1[f] = *reinterpret_cast<const short8*>(wp_h1 + ((size_t)(f * 64 + lane)) * 8);

    // ---- phase 1: gather segment means for rows base..base+15, lane = column
    for (int r16 = 0; r16 < 16; ++r16) {
        int row = base + r16;
        int e0 = rowptr[row], e1 = rowptr[row + 1];
        float acc = 0.0f;
        int j = e0;
        for (; j + 3 < e1; j += 4) {
            int s0 = csr[j], s1 = csr[j + 1], s2 = csr[j + 2], s3 = csr[j + 3];
            float v0 = b2f(evt_h[(size_t)s0 * 64 + lane]);
            float v1 = b2f(evt_h[(size_t)s1 * 64 + lane]);
            float v2 = b2f(evt_h[(size_t)s2 * 64 + lane]);
            float v3 = b2f(evt_h[(size_t)s3 * 64 + lane]);
            acc += v0 + v1 + v2 + v3;
        }
        for (; j < e1; ++j)
            acc += b2f(evt_h[(size_t)csr[j] * 64 + lane]);
        float inv = (e1 > e0) ? 1.0f / (float)(e1 - e0) : 0.0f;
        tileS[wv][r16 * 64 + lane] = f2b(acc * inv);
    }

    // ---- phase 2: MFMA head (A frags from LDS tile; wave-private, no barrier)
    short8 aA[2], aL[2];
#pragma unroll
    for (int kk = 0; kk < 2; ++kk) {
        aA[kk] = *reinterpret_cast<const short8*>(
            &tileS[wv][l15 * 64 + kk * 32 + quad * 8]);
        aL[kk] = *reinterpret_cast<const short8*>(
            loc_h + (size_t)(base + l15) * 64 + kk * 32 + quad * 8);
    }

    floatx4 acc[4];
#pragma unroll
    for (int t = 0; t < 4; ++t) acc[t] = (floatx4)0.0f;
#pragma unroll
    for (int kk = 0; kk < 2; ++kk) {
#pragma unroll
        for (int t = 0; t < 4; ++t) {
            acc[t] = __builtin_amdgcn_mfma_f32_16x16x32_bf16(
                aA[kk], bwl[t * 2 + kk], acc[t], 0, 0, 0);
            acc[t] = __builtin_amdgcn_mfma_f32_16x16x32_bf16(
                aL[kk], bwr[t * 2 + kk], acc[t], 0, 0, 0);
        }
    }

    // h2 -> LDS (row-major [16][64] bf16); C-layout: row=quad*4+r, col=t*16+l15
#pragma unroll
    for (int t = 0; t < 4; ++t) {
        float bb = loadf(bl, fbl, t * 16 + l15);
#pragma unroll
        for (int r = 0; r < 4; ++r) {
            float v = acc[t][r] + bb;
            v = v > 0.0f ? v : 0.0f;
            h2s[wv][(quad * 4 + r) * 64 + t * 16 + l15] = f2b(v);
        }
    }
    short8 aH[2];
#pragma unroll
    for (int kk = 0; kk < 2; ++kk)
        aH[kk] = *reinterpret_cast<const short8*>(
            &h2s[wv][l15 * 64 + kk * 32 + quad * 8]);

    floatx4 a1[2];
#pragma unroll
    for (int t = 0; t < 2; ++t) a1[t] = (floatx4)0.0f;
#pragma unroll
    for (int kk = 0; kk < 2; ++kk)
#pragma unroll
        for (int t = 0; t < 2; ++t)
            a1[t] = __builtin_amdgcn_mfma_f32_16x16x32_bf16(
                aH[kk], bw1[t * 2 + kk], a1[t], 0, 0, 0);

    float s[4] = {0.f, 0.f, 0.f, 0.f};
#pragma unroll
    for (int t = 0; t < 2; ++t) {
        float bb = loadf(bh1, fbh1, t * 16 + l15);
        float w2 = loadf(wh2, fwh2, t * 16 + l15);
#pragma unroll
        for (int r = 0; r < 4; ++r) {
            float v = a1[t][r] + bb;
            v = v > 0.0f ? v : 0.0f;
            s[r] += v * w2;
        }
    }
#pragma unroll
    for (int r = 0; r < 4; ++r) {
        s[r] += __shfl_xor(s[r], 1);
        s[r] += __shfl_xor(s[r], 2);
        s[r] += __shfl_xor(s[r], 4);
        s[r] += __shfl_xor(s[r], 8);
    }
    float bb2 = loadf(bh2, fbh2, 0);
#pragma unroll
    for (int r = 0; r < 4; ++r) {
        if (l15 == r) {
            int row = base + quad * 4 + r;
            float v = s[r] + bb2;
            if (fout) ((float*)out)[row] = v;
            else      ((unsigned short*)out)[row] = f2b(v);
        }
    }
}

// ---------------------------------------------------------------------------
// Workspace layout (bytes):
//   0:          evt_h    bf16 [200000,64] (25,600,000)
//   25600000:   loc_h    bf16 [100000,64] (12,800,000)
//   38400000:   csr_src  int [1M]         (4,000,000)
//   42400000:   cnt      int [100000]     (400,000)
//   42800000:   rowptr   int [100001]     (400,016)
//   43200016:   wofs     int [100000]     (400,000)
//   43600016:   bsum     int [<=128]      (4,096)
//   43604112:   wp_all   bf16 [26624]     (53,248)   (16B-aligned)
//   43657360:   flags    int[16]
// ---------------------------------------------------------------------------
extern "C" void kernel_launch(void* const* d_in, const int* in_sizes, int n_in,
                              void* d_out, int out_size, void* d_ws, size_t ws_size,
                              hipStream_t stream) {
    (void)in_sizes; (void)n_in; (void)out_size; (void)ws_size;
    const void* loc_x = d_in[0];
    const void* evt_x = d_in[1];
    const int*  eidx  = (const int*)d_in[2];
    const void* W_loc = d_in[3];
    const void* b_loc = d_in[4];
    const void* W_evt = d_in[5];
    const void* b_evt = d_in[6];
    const void* W_l   = d_in[7];
    const void* b_l   = d_in[8];
    const void* W_r   = d_in[9];
    const void* W_h1  = d_in[10];
    const void* b_h1  = d_in[11];
    const void* W_h2  = d_in[12];
    const void* b_h2  = d_in[13];

    char* ws = (char*)d_ws;
    unsigned short* evt_h  = (unsigned short*)(ws);
    unsigned short* loc_h  = (unsigned short*)(ws + 25600000);
    int*            csr    = (int*)(ws + 38400000);
    int*            cnt    = (int*)(ws + 42400000);
    int*            rowptr = (int*)(ws + 42800000);
    int*            wofs   = (int*)(ws + 43200016);
    int*            bsum   = (int*)(ws + 43600016);
    unsigned short* wp_all = (unsigned short*)(ws + 43604112);
    int*            flags  = (int*)(ws + 43657360);

    unsigned short* wp_evt = wp_all;
    unsigned short* wp_loc = wp_all + 8192;
    unsigned short* wp_l   = wp_all + 16384;
    unsigned short* wp_r   = wp_all + 20480;
    unsigned short* wp_h1  = wp_all + 24576;

    detect_zero_kernel<<<112, 256, 0, stream>>>(
        loc_x, evt_x, eidx, W_loc, b_loc, W_evt, b_evt,
        W_l, b_l, W_r, W_h1, b_h1, W_h2, b_h2, flags, (int4*)cnt);

    permute_all_kernel<<<13, 256, 0, stream>>>(W_evt, W_loc, W_l, W_r, W_h1,
                                               wp_all, flags);

    proj_kernel<<<(N_EVT + 63) / 64, 256, 0, stream>>>(evt_x, wp_evt, b_evt,
                                                       evt_h, N_EVT, flags, 1, 6);
    proj_kernel<<<(N_LOC + 63) / 64, 256, 0, stream>>>(loc_x, wp_loc, b_loc,
                                                       loc_h, N_LOC, flags, 0, 4);

    hist_kernel<<<(E_CNT + 255) / 256, 256, 0, stream>>>(eidx, cnt, flags);
    scan_sums_kernel<<<98, 256, 0, stream>>>(cnt, bsum, N_LOC);
    scan_bsum_kernel<<<1, 128, 0, stream>>>(bsum, 98);
    scan_write_kernel<<<98, 256, 0, stream>>>(cnt, bsum, rowptr, wofs, N_LOC);
    fill_kernel<<<(E_CNT + 255) / 256, 256, 0, stream>>>(eidx, wofs, csr, flags);

    gather_head_kernel<<<(NTILES + 3) / 4, 256, 0, stream>>>(
        evt_h, loc_h, rowptr, csr, wp_l, wp_r, wp_h1,
        b_l, b_h1, W_h2, b_h2, d_out, flags);
}

// Round 5
// 405.348 us; speedup vs baseline: 3.2526x; 1.0923x over previous
//
#include <hip/hip_runtime.h>

// ---------------------------------------------------------------------------
// HeteroGNN fused pipeline for MI355X (gfx950).
//   loc_h = relu(loc_x @ W_loc + b_loc)          [100000, 64]
//   evt_h = relu(evt_x @ W_evt + b_evt)          [200000, 64]
//   agg   = segment_mean(evt_h[src] -> dst)      (CSR gather, 1 wave/row)
//   h2    = relu(agg @ W_l + b_l + loc_h @ W_r)  (MFMA)
//   h1    = relu(h2 @ W_h1 + b_h1)               (MFMA)
//   out   = h1 @ W_h2 + b_h2                     [100000]
// R5: un-fuse gather from head (R4 fusion cost ~65us of TLP: 6250 serial
// waves vs 100000). detect+zero+permute merged into one launch; both projs
// into one launch. 9 launches total.
// ---------------------------------------------------------------------------

#define N_LOC 100000
#define N_EVT 200000
#define E_CNT 1000000
#define NTILES 6250   // N_LOC / 16

typedef __attribute__((ext_vector_type(8))) short short8;   // 8 x bf16
typedef __attribute__((ext_vector_type(4))) float floatx4;  // MFMA C/D frag

__device__ __forceinline__ float b2f(unsigned short u) {
    unsigned int x = ((unsigned int)u) << 16;
    return __builtin_bit_cast(float, x);
}
__device__ __forceinline__ unsigned short f2b(float f) {
    unsigned int x = __builtin_bit_cast(unsigned int, f);
    unsigned int r = (x + 0x7fffu + ((x >> 16) & 1u)) >> 16;  // RNE
    return (unsigned short)r;
}
__device__ __forceinline__ float loadf(const void* p, int f32, size_t i) {
    return f32 ? ((const float*)p)[i] : b2f(((const unsigned short*)p)[i]);
}

// ---------------------------------------------------------------------------
// KA: detect + zero + permute, one launch, 125 blocks.
//   b 0..12   : probe float-tensor dtype -> flags (1 = fp32)
//   b 13      : probe edge_index int32/int64 -> flags[2]
//   b 14..111 : zero cnt (98 x 256 int4)
//   b 112..124: permute the 5 weight mats into MFMA B-frag order (bf16),
//               self-detecting their tensor's dtype (no flag dependency).
// frag f = t*(K/32)+kk; lane l holds B[k=kk*32+(l>>4)*8+j][n=t*16+(l&15)].
// wp_all offsets (elements): evt 0, loc 8192, W_l 16384, W_r 20480, W_h1 24576
// ---------------------------------------------------------------------------
__global__ __launch_bounds__(256) void prep_kernel(
    const void* t0, const void* t1, const int* eidx,
    const void* t3, const void* t4, const void* t5, const void* t6,
    const void* t7, const void* t8, const void* t9, const void* t10,
    const void* t11, const void* t12, const void* t13,
    int* flags, int4* cnt4, unsigned short* __restrict__ wp_all) {
    int b = blockIdx.x, tid = threadIdx.x;
    __shared__ int s0, s1;

    if (b >= 14 && b < 112) {               // zero cnt
        int i = (b - 14) * 256 + tid;
        if (i < 25000) cnt4[i] = make_int4(0, 0, 0, 0);
        return;
    }

    if (b >= 112) {                          // permute, self-detecting
        int pb = b - 112;
        const void* W; int K, N, bstart, off;
        if (pb < 4)       { W = t5;  K = 128; N = 64; bstart = 0;  off = 0; }
        else if (pb < 8)  { W = t3;  K = 128; N = 64; bstart = 4;  off = 8192; }
        else if (pb < 10) { W = t7;  K = 64;  N = 64; bstart = 8;  off = 16384; }
        else if (pb < 12) { W = t9;  K = 64;  N = 64; bstart = 10; off = 20480; }
        else              { W = t10; K = 64;  N = 32; bstart = 12; off = 24576; }
        if (tid == 0) s0 = 0;
        __syncthreads();
        int nsamp = 2 * K * N; if (nsamp > 1024) nsamp = 1024;
        const unsigned short* h = (const unsigned short*)W;
        int susp = 0;
        for (int i = tid; i < nsamp; i += 256)
            if (((h[i] >> 7) & 0xFF) >= 0x90) susp++;
        if (susp) atomicAdd(&s0, susp);
        __syncthreads();
        int f32 = (s0 * 16 >= nsamp) ? 1 : 0;

        int idx  = (pb - bstart) * 256 + tid;
        int nk   = K >> 5;
        int f    = idx >> 6;
        int lane = idx & 63;
        int t  = f / nk;
        int kk = f - t * nk;
        int n  = t * 16 + (lane & 15);
        int k0 = kk * 32 + (lane >> 4) * 8;
        unsigned short tmp[8];
#pragma unroll
        for (int j = 0; j < 8; ++j) {
            size_t src = (size_t)(k0 + j) * N + n;
            tmp[j] = f32 ? f2b(((const float*)W)[src])
                         : ((const unsigned short*)W)[src];
        }
#pragma unroll
        for (int j = 0; j < 8; ++j) wp_all[(size_t)off + (size_t)idx * 8 + j] = tmp[j];
        return;
    }

    if (tid == 0) { s0 = 0; s1 = 0; }
    __syncthreads();
    if (b == 13) {   // edge_index: int64 => all odd 32-bit words zero
        if (tid < 128) {
            if (eidx[2 * tid] != 0) atomicAdd(&s0, 1);
            if (eidx[2 * tid + 1] != 0) atomicAdd(&s1, 1);
        }
        __syncthreads();
        if (tid == 0) flags[2] = (s1 == 0 && s0 > 32) ? 1 : 0;
        return;
    }
    const void* ptrs[13] = {t0, t1, t3, t4, t5, t6, t7, t8, t9, t10, t11, t12, t13};
    const int   cnts[13] = {12800000, 25600000, 8192, 64, 8192, 64,
                            4096, 64, 4096, 2048, 32, 32, 1};
    const int   slot[13] = {0, 1, 3, 4, 5, 6, 7, 8, 9, 10, 11, 12, 13};
    int nsamp = 2 * cnts[b];
    if (nsamp > 1024) nsamp = 1024;
    const unsigned short* h = (const unsigned short*)ptrs[b];
    int susp = 0;
    for (int i = tid; i < nsamp; i += 256)
        if (((h[i] >> 7) & 0xFF) >= 0x90) susp++;
    if (susp) atomicAdd(&s0, susp);
    __syncthreads();
    if (tid == 0) flags[slot[b]] = (s0 * 16 >= nsamp) ? 1 : 0;
}

// ---------------------------------------------------------------------------
// K1: both projections in one launch. blocks 0..3124: evt, 3125..4687: loc.
// Y[M,64] = relu(X[M,128] @ W[128,64] + b), MFMA 16x16x32, bf16 out.
// ---------------------------------------------------------------------------
__global__ __launch_bounds__(256) void proj_both_kernel(
    const void* __restrict__ evt_x, const void* __restrict__ loc_x,
    const unsigned short* __restrict__ wp_all,
    const void* __restrict__ b_evt, const void* __restrict__ b_loc,
    unsigned short* __restrict__ evt_h, unsigned short* __restrict__ loc_h,
    const int* __restrict__ flags) {
    int blk = blockIdx.x;
    const void* X; const unsigned short* Wp; const void* bias;
    unsigned short* Y; int M, fx, fb, bb;
    if (blk < 3125) { X = evt_x; Wp = wp_all;        bias = b_evt; Y = evt_h;
                      M = N_EVT; fx = flags[1]; fb = flags[6]; bb = blk; }
    else            { X = loc_x; Wp = wp_all + 8192; bias = b_loc; Y = loc_h;
                      M = N_LOC; fx = flags[0]; fb = flags[4]; bb = blk - 3125; }
    int tid  = threadIdx.x;
    int lane = tid & 63;
    int wv   = tid >> 6;
    int l15  = lane & 15;
    int quad = lane >> 4;
    int row_base = bb * 64 + wv * 16;

    short8 b[16];
#pragma unroll
    for (int f = 0; f < 16; ++f)
        b[f] = *reinterpret_cast<const short8*>(Wp + ((size_t)(f * 64 + lane)) * 8);

    int m = row_base + l15;
    short8 a[4];
#pragma unroll
    for (int kk = 0; kk < 4; ++kk) a[kk] = (short8)0;
    if (m < M) {
        if (fx) {
            const float* xr = (const float*)X + (size_t)m * 128 + quad * 8;
#pragma unroll
            for (int kk = 0; kk < 4; ++kk) {
                float4 p0 = *reinterpret_cast<const float4*>(xr + kk * 32);
                float4 p1 = *reinterpret_cast<const float4*>(xr + kk * 32 + 4);
                short8 v;
                v[0] = (short)f2b(p0.x); v[1] = (short)f2b(p0.y);
                v[2] = (short)f2b(p0.z); v[3] = (short)f2b(p0.w);
                v[4] = (short)f2b(p1.x); v[5] = (short)f2b(p1.y);
                v[6] = (short)f2b(p1.z); v[7] = (short)f2b(p1.w);
                a[kk] = v;
            }
        } else {
            const unsigned short* xr = (const unsigned short*)X + (size_t)m * 128 + quad * 8;
#pragma unroll
            for (int kk = 0; kk < 4; ++kk)
                a[kk] = *reinterpret_cast<const short8*>(xr + kk * 32);
        }
    }

    floatx4 acc[4];
#pragma unroll
    for (int t = 0; t < 4; ++t) acc[t] = (floatx4)0.0f;
#pragma unroll
    for (int kk = 0; kk < 4; ++kk) {
#pragma unroll
        for (int t = 0; t < 4; ++t)
            acc[t] = __builtin_amdgcn_mfma_f32_16x16x32_bf16(
                a[kk], b[t * 4 + kk], acc[t], 0, 0, 0);
    }

#pragma unroll
    for (int t = 0; t < 4; ++t) {
        float bv = loadf(bias, fb, t * 16 + l15);
#pragma unroll
        for (int r = 0; r < 4; ++r) {
            int row = row_base + quad * 4 + r;
            if (row < M) {
                float v = acc[t][r] + bv;
                v = v > 0.0f ? v : 0.0f;
                Y[(size_t)row * 64 + t * 16 + l15] = f2b(v);
            }
        }
    }
}

// ---------------------------------------------------------------------------
// K2a: histogram of destination degrees.
// ---------------------------------------------------------------------------
__global__ __launch_bounds__(256) void hist_kernel(
    const int* __restrict__ eidx, int* __restrict__ cnt,
    const int* __restrict__ flags) {
    int e = blockIdx.x * 256 + threadIdx.x;
    if (e >= E_CNT) return;
    int dst = flags[2] ? (int)((const long long*)eidx)[E_CNT + e]
                       : eidx[E_CNT + e];
    if ((unsigned)dst < (unsigned)N_LOC) atomicAdd(cnt + dst, 1);
}

// ---------------------------------------------------------------------------
// K2b: per-1024-chunk sums of cnt.
// ---------------------------------------------------------------------------
__global__ __launch_bounds__(256) void scan_sums_kernel(
    const int* __restrict__ cnt, int* __restrict__ bsum, int n) {
    __shared__ int ws[4];
    int b = blockIdx.x, tid = threadIdx.x;
    int base = b * 1024 + tid * 4;
    int s = 0;
#pragma unroll
    for (int j = 0; j < 4; ++j) {
        int i = base + j;
        if (i < n) s += cnt[i];
    }
    for (int d = 1; d < 64; d <<= 1) s += __shfl_xor(s, d);
    if ((tid & 63) == 0) ws[tid >> 6] = s;
    __syncthreads();
    if (tid == 0) bsum[b] = ws[0] + ws[1] + ws[2] + ws[3];
}

// ---------------------------------------------------------------------------
// K2c: exclusive scan of block sums (nb <= 128), single block.
// ---------------------------------------------------------------------------
__global__ void scan_bsum_kernel(int* bsum, int nb) {
    __shared__ int sh[128];
    int t = threadIdx.x;
    int v = (t < nb) ? bsum[t] : 0;
    sh[t] = v;
    __syncthreads();
    for (int d = 1; d < 128; d <<= 1) {
        int x = (t >= d) ? sh[t - d] : 0;
        __syncthreads();
        sh[t] += x;
        __syncthreads();
    }
    if (t < nb) bsum[t] = sh[t] - v;   // exclusive
}

// ---------------------------------------------------------------------------
// K2d: write rowptr (exclusive prefix) + wofs copy.
// ---------------------------------------------------------------------------
__global__ __launch_bounds__(256) void scan_write_kernel(
    const int* __restrict__ cnt, const int* __restrict__ bsum,
    int* __restrict__ rowptr, int* __restrict__ wofs, int n) {
    __shared__ int wsum[4];
    int b = blockIdx.x, tid = threadIdx.x, lane = tid & 63, wv = tid >> 6;
    int base = b * 1024 + tid * 4;
    int c[4];
    int tot = 0;
#pragma unroll
    for (int j = 0; j < 4; ++j) {
        int i = base + j;
        c[j] = (i < n) ? cnt[i] : 0;
        tot += c[j];
    }
    int sc = tot;  // inclusive wave scan
    for (int d = 1; d < 64; d <<= 1) {
        int x = __shfl_up(sc, d);
        if (lane >= d) sc += x;
    }
    if (lane == 63) wsum[wv] = sc;
    __syncthreads();
    int woff = 0;
    for (int w = 0; w < wv; ++w) woff += wsum[w];
    int excl = bsum[b] + woff + (sc - tot);
    int run = excl;
#pragma unroll
    for (int j = 0; j < 4; ++j) {
        int i = base + j;
        if (i < n) { rowptr[i] = run; wofs[i] = run; }
        run += c[j];
    }
    if (b == (int)gridDim.x - 1 && tid == 255) rowptr[n] = run;
}

// ---------------------------------------------------------------------------
// K2e: scatter edge src ids into CSR order.
// ---------------------------------------------------------------------------
__global__ __launch_bounds__(256) void fill_kernel(
    const int* __restrict__ eidx, int* __restrict__ wofs,
    int* __restrict__ csr, const int* __restrict__ flags) {
    int e = blockIdx.x * 256 + threadIdx.x;
    if (e >= E_CNT) return;
    int src, dst;
    if (flags[2]) {
        const long long* p = (const long long*)eidx;
        src = (int)p[e];
        dst = (int)p[E_CNT + e];
    } else {
        src = eidx[e];
        dst = eidx[E_CNT + e];
    }
    if ((unsigned)dst >= (unsigned)N_LOC || (unsigned)src >= (unsigned)N_EVT) return;
    int p = atomicAdd(wofs + dst, 1);
    csr[p] = src;
}

// ---------------------------------------------------------------------------
// K3: gather-mean, 1 wave per row (100K waves of TLP), lane = column.
// Predicated 4-wide edge groups (no serial tail).
// ---------------------------------------------------------------------------
__global__ __launch_bounds__(256) void aggregate_kernel(
    const unsigned short* __restrict__ evt_h,
    const int* __restrict__ rowptr, const int* __restrict__ csr,
    unsigned short* __restrict__ agg, int N) {
    int wid  = (blockIdx.x * 256 + threadIdx.x) >> 6;
    int lane = threadIdx.x & 63;
    if (wid >= N) return;
    int e0 = rowptr[wid], e1 = rowptr[wid + 1];
    float acc = 0.0f;
    for (int j = e0; j < e1; j += 4) {
        int c1 = j + 1 < e1, c2 = j + 2 < e1, c3 = j + 3 < e1;
        int s0 = csr[j];
        int s1 = csr[c1 ? j + 1 : j];
        int s2 = csr[c2 ? j + 2 : j];
        int s3 = csr[c3 ? j + 3 : j];
        float v0 = b2f(evt_h[(size_t)s0 * 64 + lane]);
        float v1 = b2f(evt_h[(size_t)s1 * 64 + lane]);
        float v2 = b2f(evt_h[(size_t)s2 * 64 + lane]);
        float v3 = b2f(evt_h[(size_t)s3 * 64 + lane]);
        acc += v0;
        if (c1) acc += v1;
        if (c2) acc += v2;
        if (c3) acc += v3;
    }
    float inv = (e1 > e0) ? 1.0f / (float)(e1 - e0) : 0.0f;
    agg[(size_t)wid * 64 + lane] = f2b(acc * inv);
}

// ---------------------------------------------------------------------------
// K4: SAGE + head via MFMA. One wave = 16-row tile; wave-private LDS.
// ---------------------------------------------------------------------------
__global__ __launch_bounds__(256) void head_kernel(
    const unsigned short* __restrict__ agg,
    const unsigned short* __restrict__ loc_h,
    const unsigned short* __restrict__ wp_all,
    const void* __restrict__ bl, const void* __restrict__ bh1,
    const void* __restrict__ wh2, const void* __restrict__ bh2,
    void* __restrict__ out, const int* __restrict__ flags) {
    __shared__ unsigned short h2s[4][16 * 64];
    int tid = threadIdx.x, lane = tid & 63, wv = tid >> 6;
    int tile = blockIdx.x * 4 + wv;
    if (tile >= NTILES) return;
    int l15 = lane & 15, quad = lane >> 4;
    int fbl = flags[8], fbh1 = flags[11], fwh2 = flags[12], fbh2 = flags[13];
    int fout = flags[0];
    int base = tile * 16;
    const unsigned short* wp_l  = wp_all + 16384;
    const unsigned short* wp_r  = wp_all + 20480;
    const unsigned short* wp_h1 = wp_all + 24576;

    short8 bwl[8], bwr[8], bw1[4];
#pragma unroll
    for (int f = 0; f < 8; ++f) {
        bwl[f] = *reinterpret_cast<const short8*>(wp_l + ((size_t)(f * 64 + lane)) * 8);
        bwr[f] = *reinterpret_cast<const short8*>(wp_r + ((size_t)(f * 64 + lane)) * 8);
    }
#pragma unroll
    for (int f = 0; f < 4; ++f)
        bw1[f] = *reinterpret_cast<const short8*>(wp_h1 + ((size_t)(f * 64 + lane)) * 8);

    short8 aA[2], aL[2];
#pragma unroll
    for (int kk = 0; kk < 2; ++kk) {
        aA[kk] = *reinterpret_cast<const short8*>(
            agg + (size_t)(base + l15) * 64 + kk * 32 + quad * 8);
        aL[kk] = *reinterpret_cast<const short8*>(
            loc_h + (size_t)(base + l15) * 64 + kk * 32 + quad * 8);
    }

    floatx4 acc[4];
#pragma unroll
    for (int t = 0; t < 4; ++t) acc[t] = (floatx4)0.0f;
#pragma unroll
    for (int kk = 0; kk < 2; ++kk) {
#pragma unroll
        for (int t = 0; t < 4; ++t) {
            acc[t] = __builtin_amdgcn_mfma_f32_16x16x32_bf16(
                aA[kk], bwl[t * 2 + kk], acc[t], 0, 0, 0);
            acc[t] = __builtin_amdgcn_mfma_f32_16x16x32_bf16(
                aL[kk], bwr[t * 2 + kk], acc[t], 0, 0, 0);
        }
    }

    // h2 -> LDS (row-major [16][64] bf16); C-layout: row=quad*4+r, col=t*16+l15
#pragma unroll
    for (int t = 0; t < 4; ++t) {
        float bb = loadf(bl, fbl, t * 16 + l15);
#pragma unroll
        for (int r = 0; r < 4; ++r) {
            float v = acc[t][r] + bb;
            v = v > 0.0f ? v : 0.0f;
            h2s[wv][(quad * 4 + r) * 64 + t * 16 + l15] = f2b(v);
        }
    }
    short8 aH[2];
#pragma unroll
    for (int kk = 0; kk < 2; ++kk)
        aH[kk] = *reinterpret_cast<const short8*>(
            &h2s[wv][l15 * 64 + kk * 32 + quad * 8]);

    floatx4 a1[2];
#pragma unroll
    for (int t = 0; t < 2; ++t) a1[t] = (floatx4)0.0f;
#pragma unroll
    for (int kk = 0; kk < 2; ++kk)
#pragma unroll
        for (int t = 0; t < 2; ++t)
            a1[t] = __builtin_amdgcn_mfma_f32_16x16x32_bf16(
                aH[kk], bw1[t * 2 + kk], a1[t], 0, 0, 0);

    float s[4] = {0.f, 0.f, 0.f, 0.f};
#pragma unroll
    for (int t = 0; t < 2; ++t) {
        float bb = loadf(bh1, fbh1, t * 16 + l15);
        float w2 = loadf(wh2, fwh2, t * 16 + l15);
#pragma unroll
        for (int r = 0; r < 4; ++r) {
            float v = a1[t][r] + bb;
            v = v > 0.0f ? v : 0.0f;
            s[r] += v * w2;
        }
    }
#pragma unroll
    for (int r = 0; r < 4; ++r) {
        s[r] += __shfl_xor(s[r], 1);
        s[r] += __shfl_xor(s[r], 2);
        s[r] += __shfl_xor(s[r], 4);
        s[r] += __shfl_xor(s[r], 8);
    }
    float bb2 = loadf(bh2, fbh2, 0);
#pragma unroll
    for (int r = 0; r < 4; ++r) {
        if (l15 == r) {
            int row = base + quad * 4 + r;
            float v = s[r] + bb2;
            if (fout) ((float*)out)[row] = v;
            else      ((unsigned short*)out)[row] = f2b(v);
        }
    }
}

// ---------------------------------------------------------------------------
// Workspace layout (bytes):
//   0:          evt_h    bf16 [200000,64] (25,600,000)
//   25600000:   loc_h    bf16 [100000,64] (12,800,000)
//   38400000:   csr_src  int [1M]         (4,000,000)
//   42400000:   cnt      int [100000]     (400,000)
//   42800000:   rowptr   int [100001]     (400,016)
//   43200016:   wofs     int [100000]     (400,000)
//   43600016:   bsum     int [<=128]      (4,096)
//   43604112:   wp_all   bf16 [26624]     (53,248)
//   43657360:   flags    int[16]          (64)
//   43657472:   agg      bf16 [100000,64] (12,800,000)   -> ends 56,457,472
// ---------------------------------------------------------------------------
extern "C" void kernel_launch(void* const* d_in, const int* in_sizes, int n_in,
                              void* d_out, int out_size, void* d_ws, size_t ws_size,
                              hipStream_t stream) {
    (void)in_sizes; (void)n_in; (void)out_size; (void)ws_size;
    const void* loc_x = d_in[0];
    const void* evt_x = d_in[1];
    const int*  eidx  = (const int*)d_in[2];
    const void* W_loc = d_in[3];
    const void* b_loc = d_in[4];
    const void* W_evt = d_in[5];
    const void* b_evt = d_in[6];
    const void* W_l   = d_in[7];
    const void* b_l   = d_in[8];
    const void* W_r   = d_in[9];
    const void* W_h1  = d_in[10];
    const void* b_h1  = d_in[11];
    const void* W_h2  = d_in[12];
    const void* b_h2  = d_in[13];

    char* ws = (char*)d_ws;
    unsigned short* evt_h  = (unsigned short*)(ws);
    unsigned short* loc_h  = (unsigned short*)(ws + 25600000);
    int*            csr    = (int*)(ws + 38400000);
    int*            cnt    = (int*)(ws + 42400000);
    int*            rowptr = (int*)(ws + 42800000);
    int*            wofs   = (int*)(ws + 43200016);
    int*            bsum   = (int*)(ws + 43600016);
    unsigned short* wp_all = (unsigned short*)(ws + 43604112);
    int*            flags  = (int*)(ws + 43657360);
    unsigned short* agg    = (unsigned short*)(ws + 43657472);

    prep_kernel<<<125, 256, 0, stream>>>(
        loc_x, evt_x, eidx, W_loc, b_loc, W_evt, b_evt,
        W_l, b_l, W_r, W_h1, b_h1, W_h2, b_h2,
        flags, (int4*)cnt, wp_all);

    proj_both_kernel<<<4688, 256, 0, stream>>>(evt_x, loc_x, wp_all,
                                               b_evt, b_loc, evt_h, loc_h, flags);

    hist_kernel<<<(E_CNT + 255) / 256, 256, 0, stream>>>(eidx, cnt, flags);
    scan_sums_kernel<<<98, 256, 0, stream>>>(cnt, bsum, N_LOC);
    scan_bsum_kernel<<<1, 128, 0, stream>>>(bsum, 98);
    scan_write_kernel<<<98, 256, 0, stream>>>(cnt, bsum, rowptr, wofs, N_LOC);
    fill_kernel<<<(E_CNT + 255) / 256, 256, 0, stream>>>(eidx, wofs, csr, flags);

    aggregate_kernel<<<(N_LOC + 3) / 4, 256, 0, stream>>>(evt_h, rowptr, csr,
                                                          agg, N_LOC);

    head_kernel<<<(NTILES + 3) / 4, 256, 0, stream>>>(
        agg, loc_h, wp_all, b_l, b_h1, W_h2, b_h2, d_out, flags);
}

// Round 6
// 349.158 us; speedup vs baseline: 3.7760x; 1.1609x over previous
//
#include <hip/hip_runtime.h>

// ---------------------------------------------------------------------------
// HeteroGNN fused pipeline for MI355X (gfx950).
//   loc_h = relu(loc_x @ W_loc + b_loc)          [100000, 64]
//   evt_h = relu(evt_x @ W_evt + b_evt)          [200000, 64]
//   agg   = segment_mean(evt_h[src] -> dst)      (bucketed CSR gather)
//   h2    = relu(agg @ W_l + b_l + loc_h @ W_r)  (MFMA)
//   h1    = relu(h2 @ W_h1 + b_h1)               (MFMA)
//   out   = h1 @ W_h2 + b_h2                     [100000]
// R6: hist/scan/fill (95us; fill alone 77us with 17x HBM write amplification
// from random 4B stores) replaced by 2-pass LDS-staged bucket sort: passA
// bins edges into 256 buckets via 128B coalesced bursts; passB builds local
// CSR per bucket entirely in LDS and flushes contiguously. 7 launches.
// ---------------------------------------------------------------------------

#define N_LOC 100000
#define N_EVT 200000
#define E_CNT 1000000
#define NTILES 6250   // N_LOC / 16
#define NBKT   256
#define BKT_L  391    // locations per bucket (255*391=99705 <= 99999)
#define CAPG   6000   // per-bucket capacity (avg 3906, sigma 62 -> +33 sigma)
#define QCAP   32     // passA LDS queue depth per bucket
#define PERB   7813   // edges per passA block (128 blocks)

typedef __attribute__((ext_vector_type(8))) short short8;   // 8 x bf16
typedef __attribute__((ext_vector_type(4))) float floatx4;  // MFMA C/D frag

__device__ __forceinline__ float b2f(unsigned short u) {
    unsigned int x = ((unsigned int)u) << 16;
    return __builtin_bit_cast(float, x);
}
__device__ __forceinline__ unsigned short f2b(float f) {
    unsigned int x = __builtin_bit_cast(unsigned int, f);
    unsigned int r = (x + 0x7fffu + ((x >> 16) & 1u)) >> 16;  // RNE
    return (unsigned short)r;
}
__device__ __forceinline__ float loadf(const void* p, int f32, size_t i) {
    return f32 ? ((const float*)p)[i] : b2f(((const unsigned short*)p)[i]);
}

// ---------------------------------------------------------------------------
// KA: detect + zero + permute, one launch, 28 blocks.
//   b 0..12 : probe float-tensor dtype -> flags (1 = fp32)
//   b 13    : probe edge_index int32/int64 -> flags[2]
//   b 14    : zero gbc[256]
//   b 15..27: permute 5 weight mats into MFMA B-frag order (self-detecting)
// wp_all offsets (elements): evt 0, loc 8192, W_l 16384, W_r 20480, W_h1 24576
// ---------------------------------------------------------------------------
__global__ __launch_bounds__(256) void prep_kernel(
    const void* t0, const void* t1, const int* eidx,
    const void* t3, const void* t4, const void* t5, const void* t6,
    const void* t7, const void* t8, const void* t9, const void* t10,
    const void* t11, const void* t12, const void* t13,
    int* flags, int* gbc, unsigned short* __restrict__ wp_all) {
    int b = blockIdx.x, tid = threadIdx.x;
    __shared__ int s0, s1;

    if (b == 14) { gbc[tid] = 0; return; }

    if (b >= 15) {                           // permute, self-detecting
        int pb = b - 15;
        const void* W; int K, N, bstart, off;
        if (pb < 4)       { W = t5;  K = 128; N = 64; bstart = 0;  off = 0; }
        else if (pb < 8)  { W = t3;  K = 128; N = 64; bstart = 4;  off = 8192; }
        else if (pb < 10) { W = t7;  K = 64;  N = 64; bstart = 8;  off = 16384; }
        else if (pb < 12) { W = t9;  K = 64;  N = 64; bstart = 10; off = 20480; }
        else              { W = t10; K = 64;  N = 32; bstart = 12; off = 24576; }
        if (tid == 0) s0 = 0;
        __syncthreads();
        int nsamp = 2 * K * N; if (nsamp > 1024) nsamp = 1024;
        const unsigned short* h = (const unsigned short*)W;
        int susp = 0;
        for (int i = tid; i < nsamp; i += 256)
            if (((h[i] >> 7) & 0xFF) >= 0x90) susp++;
        if (susp) atomicAdd(&s0, susp);
        __syncthreads();
        int f32 = (s0 * 16 >= nsamp) ? 1 : 0;

        int idx  = (pb - bstart) * 256 + tid;
        int nk   = K >> 5;
        int f    = idx >> 6;
        int lane = idx & 63;
        int t  = f / nk;
        int kk = f - t * nk;
        int n  = t * 16 + (lane & 15);
        int k0 = kk * 32 + (lane >> 4) * 8;
        unsigned short tmp[8];
#pragma unroll
        for (int j = 0; j < 8; ++j) {
            size_t src = (size_t)(k0 + j) * N + n;
            tmp[j] = f32 ? f2b(((const float*)W)[src])
                         : ((const unsigned short*)W)[src];
        }
#pragma unroll
        for (int j = 0; j < 8; ++j) wp_all[(size_t)off + (size_t)idx * 8 + j] = tmp[j];
        return;
    }

    if (tid == 0) { s0 = 0; s1 = 0; }
    __syncthreads();
    if (b == 13) {   // edge_index: int64 => all odd 32-bit words zero
        if (tid < 128) {
            if (eidx[2 * tid] != 0) atomicAdd(&s0, 1);
            if (eidx[2 * tid + 1] != 0) atomicAdd(&s1, 1);
        }
        __syncthreads();
        if (tid == 0) flags[2] = (s1 == 0 && s0 > 32) ? 1 : 0;
        return;
    }
    const void* ptrs[13] = {t0, t1, t3, t4, t5, t6, t7, t8, t9, t10, t11, t12, t13};
    const int   cnts[13] = {12800000, 25600000, 8192, 64, 8192, 64,
                            4096, 64, 4096, 2048, 32, 32, 1};
    const int   slot[13] = {0, 1, 3, 4, 5, 6, 7, 8, 9, 10, 11, 12, 13};
    int nsamp = 2 * cnts[b];
    if (nsamp > 1024) nsamp = 1024;
    const unsigned short* h = (const unsigned short*)ptrs[b];
    int susp = 0;
    for (int i = tid; i < nsamp; i += 256)
        if (((h[i] >> 7) & 0xFF) >= 0x90) susp++;
    if (susp) atomicAdd(&s0, susp);
    __syncthreads();
    if (tid == 0) flags[slot[b]] = (s0 * 16 >= nsamp) ? 1 : 0;
}

// ---------------------------------------------------------------------------
// K1: both projections in one launch. blocks 0..3124: evt, 3125..4687: loc.
// ---------------------------------------------------------------------------
__global__ __launch_bounds__(256) void proj_both_kernel(
    const void* __restrict__ evt_x, const void* __restrict__ loc_x,
    const unsigned short* __restrict__ wp_all,
    const void* __restrict__ b_evt, const void* __restrict__ b_loc,
    unsigned short* __restrict__ evt_h, unsigned short* __restrict__ loc_h,
    const int* __restrict__ flags) {
    int blk = blockIdx.x;
    const void* X; const unsigned short* Wp; const void* bias;
    unsigned short* Y; int M, fx, fb, bb;
    if (blk < 3125) { X = evt_x; Wp = wp_all;        bias = b_evt; Y = evt_h;
                      M = N_EVT; fx = flags[1]; fb = flags[6]; bb = blk; }
    else            { X = loc_x; Wp = wp_all + 8192; bias = b_loc; Y = loc_h;
                      M = N_LOC; fx = flags[0]; fb = flags[4]; bb = blk - 3125; }
    int tid  = threadIdx.x;
    int lane = tid & 63;
    int wv   = tid >> 6;
    int l15  = lane & 15;
    int quad = lane >> 4;
    int row_base = bb * 64 + wv * 16;

    short8 b[16];
#pragma unroll
    for (int f = 0; f < 16; ++f)
        b[f] = *reinterpret_cast<const short8*>(Wp + ((size_t)(f * 64 + lane)) * 8);

    int m = row_base + l15;
    short8 a[4];
#pragma unroll
    for (int kk = 0; kk < 4; ++kk) a[kk] = (short8)0;
    if (m < M) {
        if (fx) {
            const float* xr = (const float*)X + (size_t)m * 128 + quad * 8;
#pragma unroll
            for (int kk = 0; kk < 4; ++kk) {
                float4 p0 = *reinterpret_cast<const float4*>(xr + kk * 32);
                float4 p1 = *reinterpret_cast<const float4*>(xr + kk * 32 + 4);
                short8 v;
                v[0] = (short)f2b(p0.x); v[1] = (short)f2b(p0.y);
                v[2] = (short)f2b(p0.z); v[3] = (short)f2b(p0.w);
                v[4] = (short)f2b(p1.x); v[5] = (short)f2b(p1.y);
                v[6] = (short)f2b(p1.z); v[7] = (short)f2b(p1.w);
                a[kk] = v;
            }
        } else {
            const unsigned short* xr = (const unsigned short*)X + (size_t)m * 128 + quad * 8;
#pragma unroll
            for (int kk = 0; kk < 4; ++kk)
                a[kk] = *reinterpret_cast<const short8*>(xr + kk * 32);
        }
    }

    floatx4 acc[4];
#pragma unroll
    for (int t = 0; t < 4; ++t) acc[t] = (floatx4)0.0f;
#pragma unroll
    for (int kk = 0; kk < 4; ++kk) {
#pragma unroll
        for (int t = 0; t < 4; ++t)
            acc[t] = __builtin_amdgcn_mfma_f32_16x16x32_bf16(
                a[kk], b[t * 4 + kk], acc[t], 0, 0, 0);
    }

#pragma unroll
    for (int t = 0; t < 4; ++t) {
        float bv = loadf(bias, fb, t * 16 + l15);
#pragma unroll
        for (int r = 0; r < 4; ++r) {
            int row = row_base + quad * 4 + r;
            if (row < M) {
                float v = acc[t][r] + bv;
                v = v > 0.0f ? v : 0.0f;
                Y[(size_t)row * 64 + t * 16 + l15] = f2b(v);
            }
        }
    }
}

// ---------------------------------------------------------------------------
// K2a (passA): bucket edges by dst/391 via LDS queues; flush 128B bursts.
// Round-synchronous: push phase, barrier, per-bucket flush phase, barrier.
// gbc[b] ends as bucket b's exact entry count.
// ---------------------------------------------------------------------------
__global__ __launch_bounds__(256) void bucket_kernel(
    const int* __restrict__ eidx, uint2* __restrict__ bkt,
    int* __restrict__ gbc, const int* __restrict__ flags) {
    __shared__ uint2 queue[NBKT][QCAP];   // 64 KB
    __shared__ int qcnt[NBKT];
    int tid = threadIdx.x, blk = blockIdx.x;
    qcnt[tid] = 0;
    __syncthreads();
    int f64 = flags[2];
    const long long* e64 = (const long long*)eidx;
    int e0 = blk * PERB;
    int e1 = e0 + PERB; if (e1 > E_CNT) e1 = E_CNT;
    const int rounds = (PERB + 255) / 256;

    for (int r = 0; r < rounds; ++r) {
        int e = e0 + r * 256 + tid;
        if (e < e1) {
            int src, dst;
            if (f64) { src = (int)e64[e]; dst = (int)e64[E_CNT + e]; }
            else     { src = eidx[e];     dst = eidx[E_CNT + e]; }
            if ((unsigned)dst < (unsigned)N_LOC && (unsigned)src < (unsigned)N_EVT) {
                int bk = dst / BKT_L;
                int pos = atomicAdd(&qcnt[bk], 1);
                if (pos < QCAP) {
                    queue[bk][pos] = make_uint2((unsigned)src, (unsigned)dst);
                } else {   // overflow (astronomically rare): direct store
                    int p = atomicAdd(&gbc[bk], 1);
                    if (p < CAPG) bkt[(size_t)bk * CAPG + p] = make_uint2(src, dst);
                }
            }
        }
        __syncthreads();
        // flush phase: thread t owns bucket t
        int n = qcnt[tid]; if (n > QCAP) n = QCAP;
        while (n >= 16) {
            int gp = atomicAdd(&gbc[tid], 16);
            if (gp + 16 <= CAPG) {
                uint2* d = bkt + (size_t)tid * CAPG + gp;
#pragma unroll
                for (int j = 0; j < 16; ++j) d[j] = queue[tid][j];
            }
#pragma unroll
            for (int j = 16; j < QCAP; ++j) queue[tid][j - 16] = queue[tid][j];
            n -= 16;
        }
        qcnt[tid] = n;
        __syncthreads();
    }
    // tail flush
    int n = qcnt[tid]; if (n > QCAP) n = QCAP;
    if (n > 0) {
        int gp = atomicAdd(&gbc[tid], n);
        for (int j = 0; j < n; ++j)
            if (gp + j < CAPG) bkt[(size_t)tid * CAPG + gp + j] = queue[tid][j];
    }
}

// ---------------------------------------------------------------------------
// K2b: exclusive scan of 256 bucket counts.
// ---------------------------------------------------------------------------
__global__ void scan_gbc_kernel(const int* __restrict__ gbc,
                                int* __restrict__ bbase) {
    __shared__ int sh[256];
    int t = threadIdx.x;
    int v = gbc[t]; if (v > CAPG) v = CAPG;
    sh[t] = v;
    __syncthreads();
    for (int d = 1; d < 256; d <<= 1) {
        int x = (t >= d) ? sh[t - d] : 0;
        __syncthreads();
        sh[t] += x;
        __syncthreads();
    }
    bbase[t] = sh[t] - v;
}

// ---------------------------------------------------------------------------
// K2c (passB): per-bucket local CSR build in LDS; all global writes coalesced.
// ---------------------------------------------------------------------------
__global__ __launch_bounds__(256) void csr_build_kernel(
    const uint2* __restrict__ bkt, const int* __restrict__ gbc,
    const int* __restrict__ bbase,
    int* __restrict__ rowptr, int* __restrict__ csr) {
    __shared__ int lcnt[512];
    __shared__ int lscan[512];
    __shared__ int lcsr[CAPG];
    int b = blockIdx.x, tid = threadIdx.x;
    int loc0 = b * BKT_L;
    int nloc = N_LOC - loc0; if (nloc > BKT_L) nloc = BKT_L;
    int cntE = gbc[b]; if (cntE > CAPG) cntE = CAPG;
    int base = bbase[b];
    const uint2* bp = bkt + (size_t)b * CAPG;

    int i0 = tid, i1 = tid + 256;
    lcnt[i0] = 0; lcnt[i1] = 0;
    __syncthreads();
    // count
    for (int i = tid; i < cntE; i += 256) {
        int d = (int)bp[i].y - loc0;
        atomicAdd(&lcnt[d], 1);
    }
    __syncthreads();
    // inclusive scan over 512 (Hillis-Steele, 2 elems/thread)
    lscan[i0] = lcnt[i0]; lscan[i1] = lcnt[i1];
    __syncthreads();
    for (int d = 1; d < 512; d <<= 1) {
        int v0 = (i0 >= d) ? lscan[i0 - d] : 0;
        int v1 = (i1 >= d) ? lscan[i1 - d] : 0;
        __syncthreads();
        lscan[i0] += v0; lscan[i1] += v1;
        __syncthreads();
    }
    // rowptr (exclusive) + reset lcnt to cursor start
    for (int i = tid; i < nloc; i += 256) {
        int excl = lscan[i] - lcnt[i];
        rowptr[loc0 + i] = base + excl;
        lcnt[i] = excl;
    }
    if (b == NBKT - 1 && tid == 0) rowptr[N_LOC] = base + cntE;
    __syncthreads();
    // scatter into LDS csr segment
    for (int i = tid; i < cntE; i += 256) {
        uint2 pr = bp[i];
        int d = (int)pr.y - loc0;
        int p = atomicAdd(&lcnt[d], 1);
        if (p < CAPG) lcsr[p] = (int)pr.x;
    }
    __syncthreads();
    // contiguous flush
    for (int i = tid; i < cntE; i += 256) csr[base + i] = lcsr[i];
}

// ---------------------------------------------------------------------------
// K3: gather-mean, 1 wave per row, lane = column. Predicated 4-wide groups.
// ---------------------------------------------------------------------------
__global__ __launch_bounds__(256) void aggregate_kernel(
    const unsigned short* __restrict__ evt_h,
    const int* __restrict__ rowptr, const int* __restrict__ csr,
    unsigned short* __restrict__ agg, int N) {
    int wid  = (blockIdx.x * 256 + threadIdx.x) >> 6;
    int lane = threadIdx.x & 63;
    if (wid >= N) return;
    int e0 = rowptr[wid], e1 = rowptr[wid + 1];
    float acc = 0.0f;
    for (int j = e0; j < e1; j += 4) {
        int c1 = j + 1 < e1, c2 = j + 2 < e1, c3 = j + 3 < e1;
        int s0 = csr[j];
        int s1 = csr[c1 ? j + 1 : j];
        int s2 = csr[c2 ? j + 2 : j];
        int s3 = csr[c3 ? j + 3 : j];
        float v0 = b2f(evt_h[(size_t)s0 * 64 + lane]);
        float v1 = b2f(evt_h[(size_t)s1 * 64 + lane]);
        float v2 = b2f(evt_h[(size_t)s2 * 64 + lane]);
        float v3 = b2f(evt_h[(size_t)s3 * 64 + lane]);
        acc += v0;
        if (c1) acc += v1;
        if (c2) acc += v2;
        if (c3) acc += v3;
    }
    float inv = (e1 > e0) ? 1.0f / (float)(e1 - e0) : 0.0f;
    agg[(size_t)wid * 64 + lane] = f2b(acc * inv);
}

// ---------------------------------------------------------------------------
// K4: SAGE + head via MFMA. One wave = 16-row tile; wave-private LDS.
// ---------------------------------------------------------------------------
__global__ __launch_bounds__(256) void head_kernel(
    const unsigned short* __restrict__ agg,
    const unsigned short* __restrict__ loc_h,
    const unsigned short* __restrict__ wp_all,
    const void* __restrict__ bl, const void* __restrict__ bh1,
    const void* __restrict__ wh2, const void* __restrict__ bh2,
    void* __restrict__ out, const int* __restrict__ flags) {
    __shared__ unsigned short h2s[4][16 * 64];
    int tid = threadIdx.x, lane = tid & 63, wv = tid >> 6;
    int tile = blockIdx.x * 4 + wv;
    if (tile >= NTILES) return;
    int l15 = lane & 15, quad = lane >> 4;
    int fbl = flags[8], fbh1 = flags[11], fwh2 = flags[12], fbh2 = flags[13];
    int fout = flags[0];
    int base = tile * 16;
    const unsigned short* wp_l  = wp_all + 16384;
    const unsigned short* wp_r  = wp_all + 20480;
    const unsigned short* wp_h1 = wp_all + 24576;

    short8 bwl[8], bwr[8], bw1[4];
#pragma unroll
    for (int f = 0; f < 8; ++f) {
        bwl[f] = *reinterpret_cast<const short8*>(wp_l + ((size_t)(f * 64 + lane)) * 8);
        bwr[f] = *reinterpret_cast<const short8*>(wp_r + ((size_t)(f * 64 + lane)) * 8);
    }
#pragma unroll
    for (int f = 0; f < 4; ++f)
        bw1[f] = *reinterpret_cast<const short8*>(wp_h1 + ((size_t)(f * 64 + lane)) * 8);

    short8 aA[2], aL[2];
#pragma unroll
    for (int kk = 0; kk < 2; ++kk) {
        aA[kk] = *reinterpret_cast<const short8*>(
            agg + (size_t)(base + l15) * 64 + kk * 32 + quad * 8);
        aL[kk] = *reinterpret_cast<const short8*>(
            loc_h + (size_t)(base + l15) * 64 + kk * 32 + quad * 8);
    }

    floatx4 acc[4];
#pragma unroll
    for (int t = 0; t < 4; ++t) acc[t] = (floatx4)0.0f;
#pragma unroll
    for (int kk = 0; kk < 2; ++kk) {
#pragma unroll
        for (int t = 0; t < 4; ++t) {
            acc[t] = __builtin_amdgcn_mfma_f32_16x16x32_bf16(
                aA[kk], bwl[t * 2 + kk], acc[t], 0, 0, 0);
            acc[t] = __builtin_amdgcn_mfma_f32_16x16x32_bf16(
                aL[kk], bwr[t * 2 + kk], acc[t], 0, 0, 0);
        }
    }

#pragma unroll
    for (int t = 0; t < 4; ++t) {
        float bb = loadf(bl, fbl, t * 16 + l15);
#pragma unroll
        for (int r = 0; r < 4; ++r) {
            float v = acc[t][r] + bb;
            v = v > 0.0f ? v : 0.0f;
            h2s[wv][(quad * 4 + r) * 64 + t * 16 + l15] = f2b(v);
        }
    }
    short8 aH[2];
#pragma unroll
    for (int kk = 0; kk < 2; ++kk)
        aH[kk] = *reinterpret_cast<const short8*>(
            &h2s[wv][l15 * 64 + kk * 32 + quad * 8]);

    floatx4 a1[2];
#pragma unroll
    for (int t = 0; t < 2; ++t) a1[t] = (floatx4)0.0f;
#pragma unroll
    for (int kk = 0; kk < 2; ++kk)
#pragma unroll
        for (int t = 0; t < 2; ++t)
            a1[t] = __builtin_amdgcn_mfma_f32_16x16x32_bf16(
                aH[kk], bw1[t * 2 + kk], a1[t], 0, 0, 0);

    float s[4] = {0.f, 0.f, 0.f, 0.f};
#pragma unroll
    for (int t = 0; t < 2; ++t) {
        float bb = loadf(bh1, fbh1, t * 16 + l15);
        float w2 = loadf(wh2, fwh2, t * 16 + l15);
#pragma unroll
        for (int r = 0; r < 4; ++r) {
            float v = a1[t][r] + bb;
            v = v > 0.0f ? v : 0.0f;
            s[r] += v * w2;
        }
    }
#pragma unroll
    for (int r = 0; r < 4; ++r) {
        s[r] += __shfl_xor(s[r], 1);
        s[r] += __shfl_xor(s[r], 2);
        s[r] += __shfl_xor(s[r], 4);
        s[r] += __shfl_xor(s[r], 8);
    }
    float bb2 = loadf(bh2, fbh2, 0);
#pragma unroll
    for (int r = 0; r < 4; ++r) {
        if (l15 == r) {
            int row = base + quad * 4 + r;
            float v = s[r] + bb2;
            if (fout) ((float*)out)[row] = v;
            else      ((unsigned short*)out)[row] = f2b(v);
        }
    }
}

// ---------------------------------------------------------------------------
// Workspace layout (bytes):
//   0:          evt_h    bf16 [200000,64] (25,600,000)
//   25600000:   loc_h    bf16 [100000,64] (12,800,000)
//   38400000:   csr      int [1M]         (4,000,000)
//   42400000:   rowptr   int [100001]     (400,016)
//   42800016:   gbc      int [256]        (1,024)
//   42801040:   bbase    int [256]        (1,024)
//   42802064:   wp_all   bf16 [26624]     (53,248)
//   42855312:   flags    int[16]          (64)
//   42855376:   bkt uint2[256][6000] (12,288,000) / agg bf16 (12,800,000)
//               (temporally disjoint: bkt dead after csr_build, agg written
//                by aggregate afterwards; union ends 55,655,376 < 64.4 MB)
// ---------------------------------------------------------------------------
extern "C" void kernel_launch(void* const* d_in, const int* in_sizes, int n_in,
                              void* d_out, int out_size, void* d_ws, size_t ws_size,
                              hipStream_t stream) {
    (void)in_sizes; (void)n_in; (void)out_size; (void)ws_size;
    const void* loc_x = d_in[0];
    const void* evt_x = d_in[1];
    const int*  eidx  = (const int*)d_in[2];
    const void* W_loc = d_in[3];
    const void* b_loc = d_in[4];
    const void* W_evt = d_in[5];
    const void* b_evt = d_in[6];
    const void* W_l   = d_in[7];
    const void* b_l   = d_in[8];
    const void* W_r   = d_in[9];
    const void* W_h1  = d_in[10];
    const void* b_h1  = d_in[11];
    const void* W_h2  = d_in[12];
    const void* b_h2  = d_in[13];

    char* ws = (char*)d_ws;
    unsigned short* evt_h  = (unsigned short*)(ws);
    unsigned short* loc_h  = (unsigned short*)(ws + 25600000);
    int*            csr    = (int*)(ws + 38400000);
    int*            rowptr = (int*)(ws + 42400000);
    int*            gbc    = (int*)(ws + 42800016);
    int*            bbase  = (int*)(ws + 42801040);
    unsigned short* wp_all = (unsigned short*)(ws + 42802064);
    int*            flags  = (int*)(ws + 42855312);
    uint2*          bkt    = (uint2*)(ws + 42855376);
    unsigned short* agg    = (unsigned short*)(ws + 42855376);

    prep_kernel<<<28, 256, 0, stream>>>(
        loc_x, evt_x, eidx, W_loc, b_loc, W_evt, b_evt,
        W_l, b_l, W_r, W_h1, b_h1, W_h2, b_h2,
        flags, gbc, wp_all);

    proj_both_kernel<<<4688, 256, 0, stream>>>(evt_x, loc_x, wp_all,
                                               b_evt, b_loc, evt_h, loc_h, flags);

    bucket_kernel<<<128, 256, 0, stream>>>(eidx, bkt, gbc, flags);
    scan_gbc_kernel<<<1, 256, 0, stream>>>(gbc, bbase);
    csr_build_kernel<<<NBKT, 256, 0, stream>>>(bkt, gbc, bbase, rowptr, csr);

    aggregate_kernel<<<(N_LOC + 3) / 4, 256, 0, stream>>>(evt_h, rowptr, csr,
                                                          agg, N_LOC);

    head_kernel<<<(NTILES + 3) / 4, 256, 0, stream>>>(
        agg, loc_h, wp_all, b_l, b_h1, W_h2, b_h2, d_out, flags);
}